// Round 12
// baseline (356.739 us; speedup 1.0000x reference)
//
#include <hip/hip_runtime.h>
#include <hip/hip_bf16.h>

#define NNODES 331776            // 81 * 4096
#define NGRAPH 4096
#define NBUCK  2048              // buckets
#define BNODES 162               // nodes per bucket (2048*162 == 331776)
#define TE     16384             // edges per tile
#define PASSES 4                 // TE / (EB*256)   (k_hist only)
#define CAP    2560              // max edges/bucket (lambda=1953, 13.7 sigma)
#define CH     64                // tile-chunks for the 3-phase column scan
#define EB     16                // edges per thread per pass in k_hist

typedef __attribute__((ext_vector_type(8))) short bf8;   // 8 bf16 (4 VGPR)
typedef __attribute__((ext_vector_type(4))) float f4;    // 4 fp32 acc
typedef __attribute__((ext_vector_type(4))) unsigned int u32x4;

static __device__ __forceinline__ short f2bf(float x) {
    return (short)__builtin_bit_cast(unsigned short, __float2bfloat16(x));
}
static __device__ __forceinline__ float bf2f(unsigned short u) {
    return __bfloat162float(__hip_bfloat16_raw{u});
}

// ---------------- deterministic bucket sort (no global atomics) ----------------

__global__ __launch_bounds__(256) void k_hist(const int* __restrict__ dst,
                                              int* __restrict__ H, int E) {
    __shared__ int h[NBUCK];
    int t = threadIdx.x, b = blockIdx.x;
    for (int i = t; i < NBUCK; i += 256) h[i] = 0;
    __syncthreads();
    for (int pass = 0; pass < PASSES; pass++) {
        int lo = b * TE + pass * (EB * 256);
        int bins[EB]; bool ok[EB];
#pragma unroll
        for (int i = 0; i < EB; i++) {
            int e = lo + i * 256 + t;
            ok[i] = e < E;
            bins[i] = ok[i] ? (dst[e] / BNODES) : 0;
        }
#pragma unroll
        for (int i = 0; i < EB; i++)
            if (ok[i]) atomicAdd(&h[bins[i]], 1);
    }
    __syncthreads();
    for (int i = t; i < NBUCK; i += 256) H[b * NBUCK + i] = h[i];
}

// ---- 3-phase per-bin scan across tiles ----
__global__ __launch_bounds__(256) void k_colA(const int* __restrict__ H,
                                              int* __restrict__ P,
                                              int NT, int CS) {
    int idx = blockIdx.x * 256 + threadIdx.x;       // < CH*NBUCK
    int bin = idx & (NBUCK - 1);
    int chunk = idx >> 11;
    int t0 = chunk * CS, t1 = min(NT, t0 + CS);
    int s = 0;
    for (int t = t0; t < t1; t++) s += H[t * NBUCK + bin];
    P[chunk * NBUCK + bin] = s;
}

__global__ __launch_bounds__(256) void k_colB(int* __restrict__ P,
                                              int* __restrict__ T) {
    int bin = blockIdx.x * 256 + threadIdx.x;       // < NBUCK
    int s = 0;
    for (int c = 0; c < CH; c++) {
        int v = P[c * NBUCK + bin];
        P[c * NBUCK + bin] = s;
        s += v;
    }
    T[bin] = s;
}

__global__ __launch_bounds__(256) void k_colC(int* __restrict__ H,
                                              const int* __restrict__ P,
                                              int NT, int CS) {
    int idx = blockIdx.x * 256 + threadIdx.x;       // < CH*NBUCK
    int bin = idx & (NBUCK - 1);
    int chunk = idx >> 11;
    int t0 = chunk * CS, t1 = min(NT, t0 + CS);
    int s = P[chunk * NBUCK + bin];
    for (int t = t0; t < t1; t++) {
        int v = H[t * NBUCK + bin];
        H[t * NBUCK + bin] = s;
        s += v;
    }
}

// exclusive scan over the 2048 bucket totals -> Bstart[0..NBUCK]
__global__ __launch_bounds__(256) void k_binscan(const int* __restrict__ T,
                                                 int* __restrict__ Bstart) {
    __shared__ int tmp[256];
    int t = threadIdx.x;
    int base = t * 8;
    int loc[8]; int s = 0;
#pragma unroll
    for (int i = 0; i < 8; i++) { loc[i] = s; s += T[base + i]; }
    tmp[t] = s; __syncthreads();
    for (int o = 1; o < 256; o <<= 1) {
        int a = (t >= o) ? tmp[t - o] : 0;
        __syncthreads();
        tmp[t] += a;
        __syncthreads();
    }
    int excl = tmp[t] - s;
#pragma unroll
    for (int i = 0; i < 8; i++) Bstart[base + i] = excl + loc[i];
    if (t == 255) Bstart[NBUCK] = excl + s;
}

// place edges into bucket-major order; payload packs (src | dst_local<<19, es).
// R8: full-tile LDS staging -> linear readout so global writes are contiguous
// runs (~8 edges = 64B per bucket) -> line-granular write service.
__global__ __launch_bounds__(1024) void k_place(
    const int* __restrict__ src, const int* __restrict__ dst,
    const float* __restrict__ w,
    const int* __restrict__ H, const int* __restrict__ Bstart,
    int2* __restrict__ csrB, int E) {
    __shared__ int2 pb[TE];              // 128 KB sorted payload staging
    __shared__ int lstart[NBUCK + 1];    // local exclusive starts + sentinel
    __shared__ int gshift[NBUCK];        // global addr = gshift[bin] + i
    __shared__ int lcur[NBUCK];          // hist, then running cursor
    __shared__ int tsum[1024];           // scan temp
    int t = threadIdx.x, b = blockIdx.x;
    // phase 0+1: histogram
    for (int i = t; i < NBUCK; i += 1024) lcur[i] = 0;
    __syncthreads();
    {
        int bins[16];
#pragma unroll
        for (int k = 0; k < 16; k++) {
            int e = b * TE + k * 1024 + t;
            bins[k] = (e < E) ? (dst[e] / BNODES) : -1;
        }
#pragma unroll
        for (int k = 0; k < 16; k++)
            if (bins[k] >= 0) atomicAdd(&lcur[bins[k]], 1);
    }
    __syncthreads();
    // phase 2: 1024-wide scan over 2048 bins (2 bins/thread)
    int b0 = t * 2;
    int c0 = lcur[b0], c1 = lcur[b0 + 1];
    tsum[t] = c0 + c1;
    __syncthreads();
    for (int o = 1; o < 1024; o <<= 1) {
        int a = (t >= o) ? tsum[t - o] : 0;
        __syncthreads();
        tsum[t] += a;
        __syncthreads();
    }
    int excl = tsum[t] - (c0 + c1);
    lstart[b0] = excl;
    lstart[b0 + 1] = excl + c0;
    if (t == 1023) lstart[NBUCK] = excl + c0 + c1;   // S = edges in tile
    gshift[b0]     = Bstart[b0]     + H[b * NBUCK + b0]     - excl;
    gshift[b0 + 1] = Bstart[b0 + 1] + H[b * NBUCK + b0 + 1] - (excl + c0);
    lcur[b0] = excl;
    lcur[b0 + 1] = excl + c0;
    __syncthreads();
    // phase 3: place into LDS in bucket-sorted order
    {
        int dd[16], sx[16]; float wv[16]; bool ok[16];
#pragma unroll
        for (int k = 0; k < 16; k++) {
            int e = b * TE + k * 1024 + t;
            ok[k] = e < E;
            if (ok[k]) { dd[k] = dst[e]; sx[k] = src[e]; wv[k] = w[e]; }
        }
        int pk0[16]; float es[16]; int bin[16];
#pragma unroll
        for (int k = 0; k < 16; k++) {
            if (ok[k]) {
                float v = wv[k];
                float e2 = 0.f;
                if (v > 0.f)      e2 = __expf(v);
                else if (v < 0.f) e2 = -__expf(-v);
                es[k] = e2;
                bin[k] = dd[k] / BNODES;
                pk0[k] = sx[k] | ((dd[k] - bin[k] * BNODES) << 19);
            }
        }
        int p[16];
#pragma unroll
        for (int k = 0; k < 16; k++)
            if (ok[k]) p[k] = atomicAdd(&lcur[bin[k]], 1);
#pragma unroll
        for (int k = 0; k < 16; k++)
            if (ok[k]) {
                int2 pk; pk.x = pk0[k]; pk.y = __float_as_int(es[k]);
                pb[p[k]] = pk;
            }
    }
    __syncthreads();
    // phase 4: linear readout, coalesced global writes (runs per bucket)
    int S = lstart[NBUCK];
    for (int k = 0; k < 16; k++) {
        int i = k * 1024 + t;
        if (i < S) {
            int lo = 0, hi = NBUCK;                 // lstart[0]==0 <= i
            while (hi - lo > 1) {
                int mid = (lo + hi) >> 1;
                if (lstart[mid] <= i) lo = mid; else hi = mid;
            }
            csrB[gshift[lo] + i] = pb[i];
        }
    }
}

// per-bucket counting sort (in place), key = dst_local*2 + sign:
// each node's edges land [positives | negatives].
// Output payload: .x = src(19b) | (d&7)<<19 | sign<<22  (slot id for MFMA agg),
//                 .y = |es| fp32.
__global__ __launch_bounds__(256) void k_sortbucket(
    int2* __restrict__ csrB, const int* __restrict__ Bstart,
    int* __restrict__ cnt, int* __restrict__ cntp, int* __restrict__ offs) {
    __shared__ int2 pb[CAP];
    __shared__ int lcnt[BNODES * 2];
    __shared__ int lpos[BNODES * 2];
    int t = threadIdx.x, b = blockIdx.x;
    int lo = Bstart[b];
    int S  = Bstart[b + 1] - lo;
    if (S > CAP) S = CAP;                        // memory-safety guard
    for (int i = t; i < BNODES * 2; i += 256) lcnt[i] = 0;
    __syncthreads();
    for (int i = t; i < S; i += 256) {
        int2 pk = csrB[lo + i];                  // coalesced
        pb[i] = pk;
        int key = ((pk.x >> 19) << 1) | ((unsigned)pk.y >> 31);
        atomicAdd(&lcnt[key], 1);
    }
    __syncthreads();
    if (t == 0) {
        int s = 0;
        for (int i = 0; i < BNODES * 2; i++) { lpos[i] = s; s += lcnt[i]; }
    }
    __syncthreads();
    int node0 = b * BNODES;
    for (int i = t; i < BNODES; i += 256) {
        cnt[node0 + i]  = lcnt[2 * i] + lcnt[2 * i + 1];
        cntp[node0 + i] = lcnt[2 * i];
        offs[node0 + i] = lo + lpos[2 * i];
    }
    __syncthreads();
    for (int i = t; i < S; i += 256) {
        int2 pk = pb[i];
        int local = pk.x >> 19;
        int sign  = (unsigned)pk.y >> 31;
        int key = (local << 1) | sign;
        int p = atomicAdd(&lpos[key], 1);
        int d7 = (node0 + local) & 7;            // node mod 8 -> slot id bits
        int2 outv;
        outv.x = (pk.x & 0x7FFFF) | (d7 << 19) | (sign << 22);
        outv.y = pk.y & 0x7FFFFFFF;              // |es|
        csrB[lo + p] = outv;                     // bucket-local, L2-hot
    }
}

// ---------------- Layer 1 (h0 = deg, 1 feature -> 32), bf16 output ----------
// 16 lanes/node; epilogue computes 2 features per lane (f, f+16).
// Emits xtab[d] = bf16x4 (c1s*deg, c1p*hp, c1n*hn, 1.0) — the MFMA-agg A operand.

__global__ __launch_bounds__(256) void k_layer1(
    const int* __restrict__ cnt, const int* __restrict__ cntp,
    const int* __restrict__ offs, const int2* __restrict__ csr,
    float* __restrict__ spos, float* __restrict__ sneg,
    unsigned short* __restrict__ h1b,
    unsigned long long* __restrict__ xtab,
    const float* __restrict__ W1, const float* __restrict__ b1,
    const float* __restrict__ bias1,
    const float* __restrict__ c1s, const float* __restrict__ c1p,
    const float* __restrict__ c1n) {
    int t = threadIdx.x;
    int g = t >> 4, f = t & 15;           // 16 groups x 16 lanes
    int d = blockIdx.x * 16 + g;          // NNODES % 16 == 0
    int beg = offs[d];
    int len = cnt[d];
    int np  = cntp[d];
    float sp = 0.f, sn = 0.f, up = 0.f, un = 0.f;
    for (int j = 0; j < len; j += 16) {
        int rem = len - j;
        if (f < rem) {
            int2 sw = csr[beg + j + f];            // coalesced 8B/lane
            float es = __int_as_float(sw.y);        // |es|
            float degs = (float)cnt[sw.x & 0x7FFFF]; // mask slot bits
            float ep = (j + f < np) ? es : 0.f;
            float en = es - ep;
            sp += ep; sn += en;
            up = fmaf(degs, ep, up); un = fmaf(degs, en, un);
        }
    }
#pragma unroll
    for (int m = 8; m; m >>= 1) {
        sp += __shfl_xor(sp, m, 16);
        sn += __shfl_xor(sn, m, 16);
        up += __shfl_xor(up, m, 16);
        un += __shfl_xor(un, m, 16);
    }
    if (f == 0) { spos[d] = sp; sneg[d] = sn; }
    float hp = up / fmaxf(sp, 1e-20f);
    float hn = un / fmaxf(sn, 1e-20f);
    float x0 = c1s[0] * (float)len;   // deg[d] == len
    float x1 = c1p[0] * hp;
    float x2 = c1n[0] * hn;
    if (f == 0) {
        unsigned long long u0 = (unsigned short)f2bf(x0);
        unsigned long long u1 = (unsigned short)f2bf(x1);
        unsigned long long u2 = (unsigned short)f2bf(x2);
        xtab[d] = u0 | (u1 << 16) | (u2 << 32) | (0x3F80ULL << 48); // +1.0
    }
#pragma unroll
    for (int q = 0; q < 2; q++) {
        int ff = f + q * 16;
        float v = W1[ff * 3] * x0 + W1[ff * 3 + 1] * x1 + W1[ff * 3 + 2] * x2
                + b1[ff] + bias1[ff];
        v = fmaxf(v, 0.f);
        h1b[d * 32 + ff] = (unsigned short)f2bf(v);  // bf16 table (MFMA A operand)
    }
}

// ---------------- Layer-2 aggregation via MFMA --------------------------------
// Per wave: 8 nodes = 16 slots (node&7 x sign). Window = 32 edges.
//  MFMA1 (x4): H[edge16][feat16] = relu(Xe * W1T), bias folded via x3=1.
//  MFMA2 (x2): OUT[slot16][feat16] += S * H, S one-hot per edge column.
// R11: 3-stage software pipeline — load rec[w+2] || derive+gather w+1 ||
// compute w. Hides the ~500cy csr->bpermute->xtab front chain of windows
// 1..nw-1 under window w's MFMA+LDS work (only acc2 carries a dependency).

struct AggFront {
    int pk;                       // es16 | slot<<16
    unsigned long long r80, r81;  // xtab records for eh=0,1 (quad0 lanes)
};

__global__ __launch_bounds__(256) void k_agg(
    const int* __restrict__ cnt, const int* __restrict__ offs,
    const int2* __restrict__ csr,
    const float* __restrict__ spos, const float* __restrict__ sneg,
    const unsigned long long* __restrict__ xtab,
    const unsigned short* __restrict__ W1Tb,   // [4][32] bf16, row3 = b1+bias1
    unsigned short* __restrict__ hpb, unsigned short* __restrict__ hnb,
    int E) {
    __shared__ unsigned short Hl[4][32][40];   // [wave][feat][edge], stride 80B
    __shared__ unsigned short Sl[4][16][40];   // [wave][slot][edge], stride 80B
    int t = threadIdx.x;
    int wv = t >> 6, lane = t & 63;
    int col = lane & 15, quad = lane >> 4;
    int d0 = (blockIdx.x * 4 + wv) * 8;
    int beg = offs[d0];
    int totlen = 0;
#pragma unroll
    for (int i = 0; i < 8; i++) totlen += cnt[d0 + i];

    // B1 = W1T fragments (feat halves); only quad 0 (k=0..7, j<4) nonzero
    bf8 B1[2];
#pragma unroll
    for (int fh = 0; fh < 2; fh++) {
        u32x4 bw = {0u, 0u, 0u, 0u};
        if (quad == 0) {
            int n = fh * 16 + col;
            unsigned w0 = W1Tb[0 * 32 + n], w1 = W1Tb[1 * 32 + n];
            unsigned w2 = W1Tb[2 * 32 + n], w3 = W1Tb[3 * 32 + n];
            bw.x = w0 | (w1 << 16);
            bw.y = w2 | (w3 << 16);
        }
        B1[fh] = __builtin_bit_cast(bf8, bw);
    }

    f4 acc2[2] = {{0.f, 0.f, 0.f, 0.f}, {0.f, 0.f, 0.f, 0.f}};
    unsigned short (*myH)[40] = Hl[wv];
    unsigned short (*myS)[40] = Sl[wv];
    int nw = (totlen + 31) >> 5;

    // stage helpers (lambdas keep the register state explicit)
    auto LDREC = [&](int w) -> long long {
        int eidx = w * 32 + (lane & 31);
        int gidx = beg + ((eidx < totlen) ? eidx : 0);
        gidx = gidx < E ? gidx : E - 1;            // guard (empty-group case)
        return *(const long long*)(csr + gidx);    // halves duplicate
    };
    auto DERIVE = [&](long long rec, int w, AggFront& f) {
        int x = (int)rec;
        float ef = __int_as_float((int)(rec >> 32));   // |es|
        int eidx = w * 32 + (lane & 31);
        int slot = (eidx < totlen) ? (((x >> 19) & 7) * 2 + ((x >> 22) & 1)) : 255;
        unsigned es16 = (unsigned)(unsigned short)f2bf(ef);
        f.pk = (int)(es16 | ((unsigned)slot << 16));
        int xm0 = __builtin_amdgcn_ds_bpermute(col * 4, x);
        int xm1 = __builtin_amdgcn_ds_bpermute((16 + col) * 4, x);
        f.r80 = 0; f.r81 = 0;
        if (quad == 0) {
            f.r80 = xtab[(unsigned)xm0 & 0x7FFFF];     // exec-masked gathers
            f.r81 = xtab[(unsigned)xm1 & 0x7FFFF];
        }
    };

    if (nw > 0) {
        AggFront fc, fn;
        long long rec0 = LDREC(0);
        DERIVE(rec0, 0, fc);
        long long recN = (nw > 1) ? LDREC(1) : rec0;

        for (int w = 0; w < nw; w++) {
            // stage: issue next-next record load + next window's derive/gather
            long long recNN = (w + 2 < nw) ? LDREC(w + 2) : recN;
            if (w + 1 < nw) DERIVE(recN, w + 1, fn);
            recN = recNN;

            // ---- compute window w from fc ----
            int slot = ((unsigned)fc.pk >> 16);
            unsigned short es16 = (unsigned short)(fc.pk & 0xFFFF);
            {
                u32x4 z = {0u, 0u, 0u, 0u};
                *(u32x4*)&myS[lane >> 2][(lane & 3) * 8] = z;
            }
            if (lane < 32 && slot < 16)
                myS[slot][lane & 31] = es16;

            // MFMA1: H = relu(Xe * W1T) for both 16-edge halves
#pragma unroll
            for (int eh = 0; eh < 2; eh++) {
                unsigned long long r8 = eh ? fc.r81 : fc.r80;
                u32x4 av = {(unsigned)r8, (unsigned)(r8 >> 32), 0u, 0u};
                bf8 A1 = __builtin_bit_cast(bf8, av);
#pragma unroll
                for (int fh = 0; fh < 2; fh++) {
                    f4 h = {0.f, 0.f, 0.f, 0.f};
                    h = __builtin_amdgcn_mfma_f32_16x16x32_bf16(A1, B1[fh], h, 0, 0, 0);
                    float l0 = fmaxf(h[0], 0.f), h0 = fmaxf(h[1], 0.f);
                    float l1 = fmaxf(h[2], 0.f), h1 = fmaxf(h[3], 0.f);
                    unsigned u0, u1;
                    asm("v_cvt_pk_bf16_f32 %0, %1, %2" : "=v"(u0) : "v"(l0), "v"(h0));
                    asm("v_cvt_pk_bf16_f32 %0, %1, %2" : "=v"(u1) : "v"(l1), "v"(h1));
                    *(unsigned long long*)&myH[fh * 16 + col][eh * 16 + quad * 4] =
                        (unsigned long long)u0 | ((unsigned long long)u1 << 32);
                }
            }

            // A2 = S[col][quad*8..+8] (one 16B LDS read)
            bf8 A2 = *(const bf8*)&myS[col][quad * 8];

            // MFMA2: acc += S * H
#pragma unroll
            for (int fh = 0; fh < 2; fh++) {
                bf8 B2 = *(const bf8*)&myH[fh * 16 + col][quad * 8];
                acc2[fh] = __builtin_amdgcn_mfma_f32_16x16x32_bf16(A2, B2, acc2[fh], 0, 0, 0);
            }
            fc = fn;                    // rotate (garbage on last iter, unused)
        }
    }

    // ---- epilogue: normalize per slot, store bf16 ----
#pragma unroll
    for (int i = 0; i < 4; i++) {
        int slot = quad * 4 + i;
        int node = d0 + (slot >> 1);
        float s = (slot & 1) ? sneg[node] : spos[node];
        float r = 1.0f / fmaxf(s, 1e-20f);
        unsigned short* bp = (slot & 1) ? hnb : hpb;
#pragma unroll
        for (int fh = 0; fh < 2; fh++) {
            float v = acc2[fh][i] * r;
            bp[(size_t)node * 32 + fh * 16 + col] = (unsigned short)f2bf(v);
        }
    }
}

// ---------------- weight prep: bf16 transposed, scales folded ---------------

__global__ __launch_bounds__(256) void k_prep(
    const float* __restrict__ W2, const float* __restrict__ c2s,
    const float* __restrict__ c2p, const float* __restrict__ c2n,
    const float* __restrict__ k1,
    const float* __restrict__ W1, const float* __restrict__ b1,
    const float* __restrict__ bias1,
    unsigned short* __restrict__ W2sT, unsigned short* __restrict__ k1T,
    unsigned short* __restrict__ W1Tb) {
    int i = blockIdx.x * 256 + threadIdx.x;
    if (i < 96 * 32) {
        int k = i >> 5, n = i & 31;
        float sc = (k < 32) ? c2s[0] : ((k < 64) ? c2p[0] : c2n[0]);
        W2sT[i] = (unsigned short)f2bf(W2[n * 96 + k] * sc);
    } else if (i < 96 * 32 + 64 * 16) {
        int j = i - 3072;
        int k = j >> 4, o = j & 15;
        k1T[j] = (unsigned short)f2bf(k1[o * 64 + k]);
    } else if (i < 96 * 32 + 64 * 16 + 4 * 32) {
        int j = i - (3072 + 1024);
        int k = j >> 5, n = j & 31;
        float v = (k < 3) ? W1[n * 3 + k] : (b1[n] + bias1[n]);
        W1Tb[j] = (unsigned short)f2bf(v);
    }
}

// ---------------- Layer-2 MLP + conv1 via MFMA ------------------------------

__global__ __launch_bounds__(256) void k_mlp_mfma(
    const unsigned short* __restrict__ h1b,
    const unsigned short* __restrict__ hpb, const unsigned short* __restrict__ hnb,
    const unsigned short* __restrict__ W2sT, const unsigned short* __restrict__ k1T,
    const float* __restrict__ b2, const float* __restrict__ bias2,
    const float* __restrict__ bk1,
    float* __restrict__ y1) {
    __shared__ unsigned short h2s[4][16 * 32];     // per-wave transpose tile
    int t = threadIdx.x;
    int wv = t >> 6;
    int lane = t & 63;
    int col = lane & 15;
    int quad = lane >> 4;

    float bv0 = b2[col] + bias2[col];
    float bv1 = b2[col + 16] + bias2[col + 16];
    float bky = bk1[col];

    bf8 BW[2][3];
#pragma unroll
    for (int nt = 0; nt < 2; nt++)
#pragma unroll
        for (int kt = 0; kt < 3; kt++) {
            bf8 b;
#pragma unroll
            for (int j = 0; j < 8; j++)
                b[j] = (short)W2sT[(kt * 32 + quad * 8 + j) * 32 + nt * 16 + col];
            BW[nt][kt] = b;
        }
    bf8 BK[2];
#pragma unroll
    for (int kt = 0; kt < 2; kt++) {
        bf8 b;
#pragma unroll
        for (int j = 0; j < 8; j++)
            b[j] = (short)k1T[(kt * 32 + quad * 8 + j) * 16 + col];
        BK[kt] = b;
    }
    unsigned short* myT = h2s[wv];

#pragma unroll 1
    for (int g = 0; g < 4; g++) {
        int nbase = blockIdx.x * 256 + wv * 64 + g * 16;
        int node = nbase + col;                     // A-operand row m = col
        bf8 a0 = *(const bf8*)(h1b + (size_t)node * 32 + quad * 8);
        bf8 a1 = *(const bf8*)(hpb + (size_t)node * 32 + quad * 8);
        bf8 a2 = *(const bf8*)(hnb + (size_t)node * 32 + quad * 8);

        f4 acc0 = {bv0, bv0, bv0, bv0};
        f4 acc1 = {bv1, bv1, bv1, bv1};
        acc0 = __builtin_amdgcn_mfma_f32_16x16x32_bf16(a0, BW[0][0], acc0, 0, 0, 0);
        acc0 = __builtin_amdgcn_mfma_f32_16x16x32_bf16(a1, BW[0][1], acc0, 0, 0, 0);
        acc0 = __builtin_amdgcn_mfma_f32_16x16x32_bf16(a2, BW[0][2], acc0, 0, 0, 0);
        acc1 = __builtin_amdgcn_mfma_f32_16x16x32_bf16(a0, BW[1][0], acc1, 0, 0, 0);
        acc1 = __builtin_amdgcn_mfma_f32_16x16x32_bf16(a1, BW[1][1], acc1, 0, 0, 0);
        acc1 = __builtin_amdgcn_mfma_f32_16x16x32_bf16(a2, BW[1][2], acc1, 0, 0, 0);

#pragma unroll
        for (int i = 0; i < 4; i++) {
            int r = quad * 4 + i;
            myT[r * 32 + col]      = (unsigned short)f2bf(fmaxf(acc0[i], 0.f));
            myT[r * 32 + col + 16] = (unsigned short)f2bf(fmaxf(acc1[i], 0.f));
        }
        bf8 ah2 = *(const bf8*)(myT + col * 32 + quad * 8);

        f4 accy = {bky, bky, bky, bky};
        accy = __builtin_amdgcn_mfma_f32_16x16x32_bf16(a0,  BK[0], accy, 0, 0, 0);
        accy = __builtin_amdgcn_mfma_f32_16x16x32_bf16(ah2, BK[1], accy, 0, 0, 0);
#pragma unroll
        for (int i = 0; i < 4; i++)
            y1[(size_t)(nbase + quad * 4 + i) * 16 + col] = accy[i];
    }
}

// ---------------- Wfc repack: vec4-friendly layout for the head FC ----------
// W4[(c>>2)*512 + u*4 + (c&3)] = Wfc[u*416+c]: 4 consecutive input-terms
// contiguous per output -> FC reads one float4 per 4 terms, coalesced.

__global__ void k_transpose(const float* __restrict__ Wfc, float* __restrict__ W4) {
    int i = blockIdx.x * 256 + threadIdx.x;
    if (i < 128 * 416) {
        int u = i / 416, c = i - u * 416;
        W4[(c >> 2) * 512 + u * 4 + (c & 3)] = Wfc[i];
    }
}

// ---------------- Head: maxpool -> conv2 -> FC -> classifier -> log_softmax ----
// 1 graph/block, small LDS; FC uses the W4 layout: 52 float4 loads per thread
// (2-way split over 104 4-term chunks) instead of 208 scalar loads.

__global__ __launch_bounds__(256) void k_head(
    const float* __restrict__ y1, const float* __restrict__ k2,
    const float* __restrict__ bk2, const float* __restrict__ W4,
    const float* __restrict__ bfc, const float* __restrict__ Wc,
    const float* __restrict__ bc, float* __restrict__ out) {
    __shared__ float yl[1296];       // 81 positions x 16 ch, [p][ch]
    __shared__ float zl[16][41];     // after maxpool, [ch][pos<40], pad
    __shared__ float xr[416];        // conv2 out, index oc*13+t
    __shared__ float k2s[1536];
    __shared__ float fl2[256];       // FC partials
    __shared__ float fl[128];
    __shared__ float ll[10];
    int t = threadIdx.x;
    int b = blockIdx.x;
    const float4* yb4 = (const float4*)(y1 + (size_t)b * 1296);
    for (int i = t; i < 324; i += 256) ((float4*)yl)[i] = yb4[i];
    for (int i = t; i < 1536; i += 256) k2s[i] = k2[i];
    __syncthreads();
    // maxpool over position pairs (drop pos 80)
    for (int i = t; i < 640; i += 256) {
        int ic = i & 15, p = i >> 4;
        zl[ic][p] = fmaxf(yl[(2 * p) * 16 + ic], yl[(2 * p + 1) * 16 + ic]);
    }
    __syncthreads();
    // conv2: 32 out-ch x 13 positions, stride 3, k=3
    for (int i = t; i < 416; i += 256) {
        int oc = i / 13, tt = i - oc * 13;
        float acc = bk2[oc];
        for (int ic = 0; ic < 16; ic++) {
            const float* kk = &k2s[(oc * 16 + ic) * 3];
            acc += zl[ic][3 * tt]     * kk[0]
                 + zl[ic][3 * tt + 1] * kk[1]
                 + zl[ic][3 * tt + 2] * kk[2];
        }
        xr[i] = acc;
    }
    __syncthreads();
    // FC 416 -> 128: 2 threads per output, 52 float4 chunks each, coalesced W4
    {
        int u = t & 127, q = t >> 7;
        float acc = 0.f;
        const float4* xr4 = (const float4*)xr;
        for (int i4 = q * 52; i4 < q * 52 + 52; i4++) {
            float4 wv = *(const float4*)(W4 + i4 * 512 + u * 4);
            float4 xv = xr4[i4];
            acc = fmaf(xv.x, wv.x, acc);
            acc = fmaf(xv.y, wv.y, acc);
            acc = fmaf(xv.z, wv.z, acc);
            acc = fmaf(xv.w, wv.w, acc);
        }
        fl2[t] = acc;
    }
    __syncthreads();
    if (t < 128)
        fl[t] = fmaxf(fl2[t] + fl2[t + 128] + bfc[t], 0.f);
    __syncthreads();
    // classifier: 16 lanes per class, shfl reduce
    if (t < 160) {
        int c = t >> 4, l = t & 15;
        float acc = 0.f;
        for (int i = l * 8; i < l * 8 + 8; i++)
            acc += fl[i] * Wc[c * 128 + i];
        for (int m = 8; m; m >>= 1) acc += __shfl_down(acc, m, 16);
        if (l == 0) ll[c] = acc + bc[c];
    }
    __syncthreads();
    if (t < 10) {
        float m = -1e30f;
        for (int c = 0; c < 10; c++) m = fmaxf(m, ll[c]);
        float s = 0.f;
        for (int c = 0; c < 10; c++) s += __expf(ll[c] - m);
        out[b * 10 + t] = ll[t] - m - __logf(s);
    }
}

// ---------------- launch ----------------

extern "C" void kernel_launch(void* const* d_in, const int* in_sizes, int n_in,
                              void* d_out, int out_size, void* d_ws, size_t ws_size,
                              hipStream_t stream) {
    const int*   src   = (const int*)d_in[0];
    const int*   dst   = (const int*)d_in[1];
    const float* w     = (const float*)d_in[2];
    const float* W1    = (const float*)d_in[4];
    const float* b1    = (const float*)d_in[5];
    const float* bias1 = (const float*)d_in[6];
    const float* c1s   = (const float*)d_in[7];
    const float* c1p   = (const float*)d_in[8];
    const float* c1n   = (const float*)d_in[9];
    const float* W2    = (const float*)d_in[10];
    const float* b2    = (const float*)d_in[11];
    const float* bias2 = (const float*)d_in[12];
    const float* c2s   = (const float*)d_in[13];
    const float* c2p   = (const float*)d_in[14];
    const float* c2n   = (const float*)d_in[15];
    const float* k1    = (const float*)d_in[16];
    const float* bk1   = (const float*)d_in[17];
    const float* k2    = (const float*)d_in[18];
    const float* bk2   = (const float*)d_in[19];
    const float* Wfc   = (const float*)d_in[20];
    const float* bfc   = (const float*)d_in[21];
    const float* Wc    = (const float*)d_in[22];
    const float* bc    = (const float*)d_in[23];
    const int E = in_sizes[0];
    const int NT = (E + TE - 1) / TE;
    const int CS = (NT + CH - 1) / CH;

    // workspace carve (256B aligned) — xtab aliases y1 (read before y1 written)
    size_t off = 0;
    auto carve = [&](size_t bytes) -> char* {
        char* p = (char*)d_ws + off;
        off = (off + bytes + 255) & ~(size_t)255;
        return p;
    };
    int*   cnt    = (int*)  carve((size_t)NNODES * 4);
    int*   cntp   = (int*)  carve((size_t)NNODES * 4);
    int*   offs   = (int*)  carve((size_t)NNODES * 4);
    int2*  csrB   = (int2*) carve((size_t)E * 8);
    int*   H      = (int*)  carve((size_t)NT * NBUCK * 4);
    int*   P      = (int*)  carve((size_t)CH * NBUCK * 4);
    int*   T      = (int*)  carve((size_t)NBUCK * 4);
    int*   Bstart = (int*)  carve((size_t)(NBUCK + 1) * 4);
    float* spos   = (float*)carve((size_t)NNODES * 4);
    float* sneg   = (float*)carve((size_t)NNODES * 4);
    unsigned short* h1b = (unsigned short*)carve((size_t)NNODES * 32 * 2);
    unsigned short* hpb = (unsigned short*)carve((size_t)NNODES * 32 * 2);
    unsigned short* hnb = (unsigned short*)carve((size_t)NNODES * 32 * 2);
    float* y1     = (float*)carve((size_t)NNODES * 16 * 4);
    float* WfcT   = (float*)carve((size_t)128 * 416 * 4);
    unsigned short* W2sT = (unsigned short*)carve((size_t)96 * 32 * 2);
    unsigned short* k1T  = (unsigned short*)carve((size_t)64 * 16 * 2);
    unsigned short* W1Tb = (unsigned short*)carve((size_t)4 * 32 * 2);
    unsigned long long* xtab = (unsigned long long*)y1;  // alias: 2.65MB << y1
    (void)ws_size;

    k_hist      <<<NT, 256, 0, stream>>>(dst, H, E);
    k_colA      <<<CH * NBUCK / 256, 256, 0, stream>>>(H, P, NT, CS);
    k_colB      <<<NBUCK / 256, 256, 0, stream>>>(P, T);
    k_colC      <<<CH * NBUCK / 256, 256, 0, stream>>>(H, P, NT, CS);
    k_binscan   <<<1, 256, 0, stream>>>(T, Bstart);
    k_place     <<<NT, 1024, 0, stream>>>(src, dst, w, H, Bstart, csrB, E);
    k_sortbucket<<<NBUCK, 256, 0, stream>>>(csrB, Bstart, cnt, cntp, offs);
    k_layer1    <<<NNODES / 16, 256, 0, stream>>>(cnt, cntp, offs, csrB,
                                                  spos, sneg, h1b, xtab,
                                                  W1, b1, bias1, c1s, c1p, c1n);
    k_prep      <<<17, 256, 0, stream>>>(W2, c2s, c2p, c2n, k1,
                                         W1, b1, bias1, W2sT, k1T, W1Tb);
    k_transpose <<<(128 * 416 + 255) / 256, 256, 0, stream>>>(Wfc, WfcT);
    k_agg       <<<NNODES / 32, 256, 0, stream>>>(cnt, offs, csrB,
                                                  spos, sneg, xtab, W1Tb,
                                                  hpb, hnb, E);
    k_mlp_mfma  <<<NNODES / 256, 256, 0, stream>>>(h1b, hpb, hnb, W2sT, k1T,
                                                   b2, bias2, bk1, y1);
    k_head      <<<NGRAPH, 256, 0, stream>>>(y1, k2, bk2, WfcT, bfc, Wc, bc,
                                             (float*)d_out);
}

// Round 13
// 354.409 us; speedup vs baseline: 1.0066x; 1.0066x over previous
//
#include <hip/hip_runtime.h>
#include <hip/hip_bf16.h>

#define NNODES 331776            // 81 * 4096
#define NGRAPH 4096
#define NBUCK  2048              // buckets
#define BNODES 162               // nodes per bucket (2048*162 == 331776)
#define TE     16384             // edges per tile
#define PASSES 4                 // TE / (EB*256)   (k_hist only)
#define CAP    2560              // max edges/bucket (lambda=1953, 13.7 sigma)
#define CH     64                // tile-chunks for the 3-phase column scan
#define EB     16                // edges per thread per pass in k_hist

typedef __attribute__((ext_vector_type(8))) short bf8;   // 8 bf16 (4 VGPR)
typedef __attribute__((ext_vector_type(4))) float f4;    // 4 fp32 acc
typedef __attribute__((ext_vector_type(4))) unsigned int u32x4;

static __device__ __forceinline__ short f2bf(float x) {
    return (short)__builtin_bit_cast(unsigned short, __float2bfloat16(x));
}
static __device__ __forceinline__ float bf2f(unsigned short u) {
    return __bfloat162float(__hip_bfloat16_raw{u});
}

// ---------------- deterministic bucket sort (no global atomics) ----------------

__global__ __launch_bounds__(256) void k_hist(const int* __restrict__ dst,
                                              int* __restrict__ H, int E) {
    __shared__ int h[NBUCK];
    int t = threadIdx.x, b = blockIdx.x;
    for (int i = t; i < NBUCK; i += 256) h[i] = 0;
    __syncthreads();
    for (int pass = 0; pass < PASSES; pass++) {
        int lo = b * TE + pass * (EB * 256);
        int bins[EB]; bool ok[EB];
#pragma unroll
        for (int i = 0; i < EB; i++) {
            int e = lo + i * 256 + t;
            ok[i] = e < E;
            bins[i] = ok[i] ? (dst[e] / BNODES) : 0;
        }
#pragma unroll
        for (int i = 0; i < EB; i++)
            if (ok[i]) atomicAdd(&h[bins[i]], 1);
    }
    __syncthreads();
    for (int i = t; i < NBUCK; i += 256) H[b * NBUCK + i] = h[i];
}

// ---- 3-phase per-bin scan across tiles ----
__global__ __launch_bounds__(256) void k_colA(const int* __restrict__ H,
                                              int* __restrict__ P,
                                              int NT, int CS) {
    int idx = blockIdx.x * 256 + threadIdx.x;       // < CH*NBUCK
    int bin = idx & (NBUCK - 1);
    int chunk = idx >> 11;
    int t0 = chunk * CS, t1 = min(NT, t0 + CS);
    int s = 0;
    for (int t = t0; t < t1; t++) s += H[t * NBUCK + bin];
    P[chunk * NBUCK + bin] = s;
}

__global__ __launch_bounds__(256) void k_colB(int* __restrict__ P,
                                              int* __restrict__ T) {
    int bin = blockIdx.x * 256 + threadIdx.x;       // < NBUCK
    int s = 0;
    for (int c = 0; c < CH; c++) {
        int v = P[c * NBUCK + bin];
        P[c * NBUCK + bin] = s;
        s += v;
    }
    T[bin] = s;
}

__global__ __launch_bounds__(256) void k_colC(int* __restrict__ H,
                                              const int* __restrict__ P,
                                              int NT, int CS) {
    int idx = blockIdx.x * 256 + threadIdx.x;       // < CH*NBUCK
    int bin = idx & (NBUCK - 1);
    int chunk = idx >> 11;
    int t0 = chunk * CS, t1 = min(NT, t0 + CS);
    int s = P[chunk * NBUCK + bin];
    for (int t = t0; t < t1; t++) {
        int v = H[t * NBUCK + bin];
        H[t * NBUCK + bin] = s;
        s += v;
    }
}

// exclusive scan over the 2048 bucket totals -> Bstart[0..NBUCK]
__global__ __launch_bounds__(256) void k_binscan(const int* __restrict__ T,
                                                 int* __restrict__ Bstart) {
    __shared__ int tmp[256];
    int t = threadIdx.x;
    int base = t * 8;
    int loc[8]; int s = 0;
#pragma unroll
    for (int i = 0; i < 8; i++) { loc[i] = s; s += T[base + i]; }
    tmp[t] = s; __syncthreads();
    for (int o = 1; o < 256; o <<= 1) {
        int a = (t >= o) ? tmp[t - o] : 0;
        __syncthreads();
        tmp[t] += a;
        __syncthreads();
    }
    int excl = tmp[t] - s;
#pragma unroll
    for (int i = 0; i < 8; i++) Bstart[base + i] = excl + loc[i];
    if (t == 255) Bstart[NBUCK] = excl + s;
}

// place edges into bucket-major order; payload packs (src | dst_local<<19, es).
// R8: full-tile LDS staging -> linear readout so global writes are contiguous
// runs (~8 edges = 64B per bucket) -> line-granular write service.
__global__ __launch_bounds__(1024) void k_place(
    const int* __restrict__ src, const int* __restrict__ dst,
    const float* __restrict__ w,
    const int* __restrict__ H, const int* __restrict__ Bstart,
    int2* __restrict__ csrB, int E) {
    __shared__ int2 pb[TE];              // 128 KB sorted payload staging
    __shared__ int lstart[NBUCK + 1];    // local exclusive starts + sentinel
    __shared__ int gshift[NBUCK];        // global addr = gshift[bin] + i
    __shared__ int lcur[NBUCK];          // hist, then running cursor
    __shared__ int tsum[1024];           // scan temp
    int t = threadIdx.x, b = blockIdx.x;
    // phase 0+1: histogram
    for (int i = t; i < NBUCK; i += 1024) lcur[i] = 0;
    __syncthreads();
    {
        int bins[16];
#pragma unroll
        for (int k = 0; k < 16; k++) {
            int e = b * TE + k * 1024 + t;
            bins[k] = (e < E) ? (dst[e] / BNODES) : -1;
        }
#pragma unroll
        for (int k = 0; k < 16; k++)
            if (bins[k] >= 0) atomicAdd(&lcur[bins[k]], 1);
    }
    __syncthreads();
    // phase 2: 1024-wide scan over 2048 bins (2 bins/thread)
    int b0 = t * 2;
    int c0 = lcur[b0], c1 = lcur[b0 + 1];
    tsum[t] = c0 + c1;
    __syncthreads();
    for (int o = 1; o < 1024; o <<= 1) {
        int a = (t >= o) ? tsum[t - o] : 0;
        __syncthreads();
        tsum[t] += a;
        __syncthreads();
    }
    int excl = tsum[t] - (c0 + c1);
    lstart[b0] = excl;
    lstart[b0 + 1] = excl + c0;
    if (t == 1023) lstart[NBUCK] = excl + c0 + c1;   // S = edges in tile
    gshift[b0]     = Bstart[b0]     + H[b * NBUCK + b0]     - excl;
    gshift[b0 + 1] = Bstart[b0 + 1] + H[b * NBUCK + b0 + 1] - (excl + c0);
    lcur[b0] = excl;
    lcur[b0 + 1] = excl + c0;
    __syncthreads();
    // phase 3: place into LDS in bucket-sorted order
    {
        int dd[16], sx[16]; float wv[16]; bool ok[16];
#pragma unroll
        for (int k = 0; k < 16; k++) {
            int e = b * TE + k * 1024 + t;
            ok[k] = e < E;
            if (ok[k]) { dd[k] = dst[e]; sx[k] = src[e]; wv[k] = w[e]; }
        }
        int pk0[16]; float es[16]; int bin[16];
#pragma unroll
        for (int k = 0; k < 16; k++) {
            if (ok[k]) {
                float v = wv[k];
                float e2 = 0.f;
                if (v > 0.f)      e2 = __expf(v);
                else if (v < 0.f) e2 = -__expf(-v);
                es[k] = e2;
                bin[k] = dd[k] / BNODES;
                pk0[k] = sx[k] | ((dd[k] - bin[k] * BNODES) << 19);
            }
        }
        int p[16];
#pragma unroll
        for (int k = 0; k < 16; k++)
            if (ok[k]) p[k] = atomicAdd(&lcur[bin[k]], 1);
#pragma unroll
        for (int k = 0; k < 16; k++)
            if (ok[k]) {
                int2 pk; pk.x = pk0[k]; pk.y = __float_as_int(es[k]);
                pb[p[k]] = pk;
            }
    }
    __syncthreads();
    // phase 4: linear readout, coalesced global writes (runs per bucket)
    int S = lstart[NBUCK];
    for (int k = 0; k < 16; k++) {
        int i = k * 1024 + t;
        if (i < S) {
            int lo = 0, hi = NBUCK;                 // lstart[0]==0 <= i
            while (hi - lo > 1) {
                int mid = (lo + hi) >> 1;
                if (lstart[mid] <= i) lo = mid; else hi = mid;
            }
            csrB[gshift[lo] + i] = pb[i];
        }
    }
}

// per-bucket counting sort (in place), key = dst_local*2 + sign:
// each node's edges land [positives | negatives].
// Output payload: .x = src(19b) | (d&7)<<19 | sign<<22  (slot id for MFMA agg),
//                 .y = |es| fp32.
__global__ __launch_bounds__(256) void k_sortbucket(
    int2* __restrict__ csrB, const int* __restrict__ Bstart,
    int* __restrict__ cnt, int* __restrict__ cntp, int* __restrict__ offs) {
    __shared__ int2 pb[CAP];
    __shared__ int lcnt[BNODES * 2];
    __shared__ int lpos[BNODES * 2];
    int t = threadIdx.x, b = blockIdx.x;
    int lo = Bstart[b];
    int S  = Bstart[b + 1] - lo;
    if (S > CAP) S = CAP;                        // memory-safety guard
    for (int i = t; i < BNODES * 2; i += 256) lcnt[i] = 0;
    __syncthreads();
    for (int i = t; i < S; i += 256) {
        int2 pk = csrB[lo + i];                  // coalesced
        pb[i] = pk;
        int key = ((pk.x >> 19) << 1) | ((unsigned)pk.y >> 31);
        atomicAdd(&lcnt[key], 1);
    }
    __syncthreads();
    if (t == 0) {
        int s = 0;
        for (int i = 0; i < BNODES * 2; i++) { lpos[i] = s; s += lcnt[i]; }
    }
    __syncthreads();
    int node0 = b * BNODES;
    for (int i = t; i < BNODES; i += 256) {
        cnt[node0 + i]  = lcnt[2 * i] + lcnt[2 * i + 1];
        cntp[node0 + i] = lcnt[2 * i];
        offs[node0 + i] = lo + lpos[2 * i];
    }
    __syncthreads();
    for (int i = t; i < S; i += 256) {
        int2 pk = pb[i];
        int local = pk.x >> 19;
        int sign  = (unsigned)pk.y >> 31;
        int key = (local << 1) | sign;
        int p = atomicAdd(&lpos[key], 1);
        int d7 = (node0 + local) & 7;            // node mod 8 -> slot id bits
        int2 outv;
        outv.x = (pk.x & 0x7FFFF) | (d7 << 19) | (sign << 22);
        outv.y = pk.y & 0x7FFFFFFF;              // |es|
        csrB[lo + p] = outv;                     // bucket-local, L2-hot
    }
}

// ---------------- Layer 1 (h0 = deg, 1 feature -> 32), bf16 output ----------
// 16 lanes/node; epilogue computes 2 features per lane (f, f+16).
// Emits xtab[d] = bf16x4 (c1s*deg, c1p*hp, c1n*hn, 1.0) — the MFMA-agg A operand.

__global__ __launch_bounds__(256) void k_layer1(
    const int* __restrict__ cnt, const int* __restrict__ cntp,
    const int* __restrict__ offs, const int2* __restrict__ csr,
    float* __restrict__ spos, float* __restrict__ sneg,
    unsigned short* __restrict__ h1b,
    unsigned long long* __restrict__ xtab,
    const float* __restrict__ W1, const float* __restrict__ b1,
    const float* __restrict__ bias1,
    const float* __restrict__ c1s, const float* __restrict__ c1p,
    const float* __restrict__ c1n) {
    int t = threadIdx.x;
    int g = t >> 4, f = t & 15;           // 16 groups x 16 lanes
    int d = blockIdx.x * 16 + g;          // NNODES % 16 == 0
    int beg = offs[d];
    int len = cnt[d];
    int np  = cntp[d];
    float sp = 0.f, sn = 0.f, up = 0.f, un = 0.f;
    for (int j = 0; j < len; j += 16) {
        int rem = len - j;
        if (f < rem) {
            int2 sw = csr[beg + j + f];            // coalesced 8B/lane
            float es = __int_as_float(sw.y);        // |es|
            float degs = (float)cnt[sw.x & 0x7FFFF]; // mask slot bits
            float ep = (j + f < np) ? es : 0.f;
            float en = es - ep;
            sp += ep; sn += en;
            up = fmaf(degs, ep, up); un = fmaf(degs, en, un);
        }
    }
#pragma unroll
    for (int m = 8; m; m >>= 1) {
        sp += __shfl_xor(sp, m, 16);
        sn += __shfl_xor(sn, m, 16);
        up += __shfl_xor(up, m, 16);
        un += __shfl_xor(un, m, 16);
    }
    if (f == 0) { spos[d] = sp; sneg[d] = sn; }
    float hp = up / fmaxf(sp, 1e-20f);
    float hn = un / fmaxf(sn, 1e-20f);
    float x0 = c1s[0] * (float)len;   // deg[d] == len
    float x1 = c1p[0] * hp;
    float x2 = c1n[0] * hn;
    if (f == 0) {
        unsigned long long u0 = (unsigned short)f2bf(x0);
        unsigned long long u1 = (unsigned short)f2bf(x1);
        unsigned long long u2 = (unsigned short)f2bf(x2);
        xtab[d] = u0 | (u1 << 16) | (u2 << 32) | (0x3F80ULL << 48); // +1.0
    }
#pragma unroll
    for (int q = 0; q < 2; q++) {
        int ff = f + q * 16;
        float v = W1[ff * 3] * x0 + W1[ff * 3 + 1] * x1 + W1[ff * 3 + 2] * x2
                + b1[ff] + bias1[ff];
        v = fmaxf(v, 0.f);
        h1b[d * 32 + ff] = (unsigned short)f2bf(v);  // bf16 table (MFMA A operand)
    }
}

// ---------------- Layer-2 aggregation via MFMA --------------------------------
// Per wave: 8 nodes = 16 slots (node&7 x sign). Window = 32 edges.
//  MFMA1 (x4): H[edge16][feat16] = relu(Xe * W1T), bias folded via x3=1.
//  MFMA2 (x2): OUT[slot16][feat16] += S * H, S one-hot per edge column.
// R11: 3-stage software pipeline — load rec[w+2] || derive+gather w+1 ||
// compute w. Hides the ~500cy csr->bpermute->xtab front chain of windows
// 1..nw-1 under window w's MFMA+LDS work (only acc2 carries a dependency).

struct AggFront {
    int pk;                       // es16 | slot<<16
    unsigned long long r80, r81;  // xtab records for eh=0,1 (quad0 lanes)
};

__global__ __launch_bounds__(256) void k_agg(
    const int* __restrict__ cnt, const int* __restrict__ offs,
    const int2* __restrict__ csr,
    const float* __restrict__ spos, const float* __restrict__ sneg,
    const unsigned long long* __restrict__ xtab,
    const unsigned short* __restrict__ W1Tb,   // [4][32] bf16, row3 = b1+bias1
    unsigned short* __restrict__ hpb, unsigned short* __restrict__ hnb,
    int E) {
    __shared__ unsigned short Hl[4][32][40];   // [wave][feat][edge], stride 80B
    __shared__ unsigned short Sl[4][16][40];   // [wave][slot][edge], stride 80B
    int t = threadIdx.x;
    int wv = t >> 6, lane = t & 63;
    int col = lane & 15, quad = lane >> 4;
    int d0 = (blockIdx.x * 4 + wv) * 8;
    int beg = offs[d0];
    int totlen = 0;
#pragma unroll
    for (int i = 0; i < 8; i++) totlen += cnt[d0 + i];

    // B1 = W1T fragments (feat halves); only quad 0 (k=0..7, j<4) nonzero
    bf8 B1[2];
#pragma unroll
    for (int fh = 0; fh < 2; fh++) {
        u32x4 bw = {0u, 0u, 0u, 0u};
        if (quad == 0) {
            int n = fh * 16 + col;
            unsigned w0 = W1Tb[0 * 32 + n], w1 = W1Tb[1 * 32 + n];
            unsigned w2 = W1Tb[2 * 32 + n], w3 = W1Tb[3 * 32 + n];
            bw.x = w0 | (w1 << 16);
            bw.y = w2 | (w3 << 16);
        }
        B1[fh] = __builtin_bit_cast(bf8, bw);
    }

    f4 acc2[2] = {{0.f, 0.f, 0.f, 0.f}, {0.f, 0.f, 0.f, 0.f}};
    unsigned short (*myH)[40] = Hl[wv];
    unsigned short (*myS)[40] = Sl[wv];
    int nw = (totlen + 31) >> 5;

    // stage helpers (lambdas keep the register state explicit)
    auto LDREC = [&](int w) -> long long {
        int eidx = w * 32 + (lane & 31);
        int gidx = beg + ((eidx < totlen) ? eidx : 0);
        gidx = gidx < E ? gidx : E - 1;            // guard (empty-group case)
        return *(const long long*)(csr + gidx);    // halves duplicate
    };
    auto DERIVE = [&](long long rec, int w, AggFront& f) {
        int x = (int)rec;
        float ef = __int_as_float((int)(rec >> 32));   // |es|
        int eidx = w * 32 + (lane & 31);
        int slot = (eidx < totlen) ? (((x >> 19) & 7) * 2 + ((x >> 22) & 1)) : 255;
        unsigned es16 = (unsigned)(unsigned short)f2bf(ef);
        f.pk = (int)(es16 | ((unsigned)slot << 16));
        int xm0 = __builtin_amdgcn_ds_bpermute(col * 4, x);
        int xm1 = __builtin_amdgcn_ds_bpermute((16 + col) * 4, x);
        f.r80 = 0; f.r81 = 0;
        if (quad == 0) {
            f.r80 = xtab[(unsigned)xm0 & 0x7FFFF];     // exec-masked gathers
            f.r81 = xtab[(unsigned)xm1 & 0x7FFFF];
        }
    };

    if (nw > 0) {
        AggFront fc, fn;
        long long rec0 = LDREC(0);
        DERIVE(rec0, 0, fc);
        long long recN = (nw > 1) ? LDREC(1) : rec0;

        for (int w = 0; w < nw; w++) {
            // stage: issue next-next record load + next window's derive/gather
            long long recNN = (w + 2 < nw) ? LDREC(w + 2) : recN;
            if (w + 1 < nw) DERIVE(recN, w + 1, fn);
            recN = recNN;

            // ---- compute window w from fc ----
            int slot = ((unsigned)fc.pk >> 16);
            unsigned short es16 = (unsigned short)(fc.pk & 0xFFFF);
            {
                u32x4 z = {0u, 0u, 0u, 0u};
                *(u32x4*)&myS[lane >> 2][(lane & 3) * 8] = z;
            }
            if (lane < 32 && slot < 16)
                myS[slot][lane & 31] = es16;

            // MFMA1: H = relu(Xe * W1T) for both 16-edge halves
#pragma unroll
            for (int eh = 0; eh < 2; eh++) {
                unsigned long long r8 = eh ? fc.r81 : fc.r80;
                u32x4 av = {(unsigned)r8, (unsigned)(r8 >> 32), 0u, 0u};
                bf8 A1 = __builtin_bit_cast(bf8, av);
#pragma unroll
                for (int fh = 0; fh < 2; fh++) {
                    f4 h = {0.f, 0.f, 0.f, 0.f};
                    h = __builtin_amdgcn_mfma_f32_16x16x32_bf16(A1, B1[fh], h, 0, 0, 0);
                    float l0 = fmaxf(h[0], 0.f), h0 = fmaxf(h[1], 0.f);
                    float l1 = fmaxf(h[2], 0.f), h1 = fmaxf(h[3], 0.f);
                    unsigned u0, u1;
                    asm("v_cvt_pk_bf16_f32 %0, %1, %2" : "=v"(u0) : "v"(l0), "v"(h0));
                    asm("v_cvt_pk_bf16_f32 %0, %1, %2" : "=v"(u1) : "v"(l1), "v"(h1));
                    *(unsigned long long*)&myH[fh * 16 + col][eh * 16 + quad * 4] =
                        (unsigned long long)u0 | ((unsigned long long)u1 << 32);
                }
            }

            // A2 = S[col][quad*8..+8] (one 16B LDS read)
            bf8 A2 = *(const bf8*)&myS[col][quad * 8];

            // MFMA2: acc += S * H
#pragma unroll
            for (int fh = 0; fh < 2; fh++) {
                bf8 B2 = *(const bf8*)&myH[fh * 16 + col][quad * 8];
                acc2[fh] = __builtin_amdgcn_mfma_f32_16x16x32_bf16(A2, B2, acc2[fh], 0, 0, 0);
            }
            fc = fn;                    // rotate (garbage on last iter, unused)
        }
    }

    // ---- epilogue: normalize per slot, store bf16 ----
#pragma unroll
    for (int i = 0; i < 4; i++) {
        int slot = quad * 4 + i;
        int node = d0 + (slot >> 1);
        float s = (slot & 1) ? sneg[node] : spos[node];
        float r = 1.0f / fmaxf(s, 1e-20f);
        unsigned short* bp = (slot & 1) ? hnb : hpb;
#pragma unroll
        for (int fh = 0; fh < 2; fh++) {
            float v = acc2[fh][i] * r;
            bp[(size_t)node * 32 + fh * 16 + col] = (unsigned short)f2bf(v);
        }
    }
}

// ---------------- weight prep: bf16 transposed, scales folded ---------------

__global__ __launch_bounds__(256) void k_prep(
    const float* __restrict__ W2, const float* __restrict__ c2s,
    const float* __restrict__ c2p, const float* __restrict__ c2n,
    const float* __restrict__ k1,
    const float* __restrict__ W1, const float* __restrict__ b1,
    const float* __restrict__ bias1,
    unsigned short* __restrict__ W2sT, unsigned short* __restrict__ k1T,
    unsigned short* __restrict__ W1Tb) {
    int i = blockIdx.x * 256 + threadIdx.x;
    if (i < 96 * 32) {
        int k = i >> 5, n = i & 31;
        float sc = (k < 32) ? c2s[0] : ((k < 64) ? c2p[0] : c2n[0]);
        W2sT[i] = (unsigned short)f2bf(W2[n * 96 + k] * sc);
    } else if (i < 96 * 32 + 64 * 16) {
        int j = i - 3072;
        int k = j >> 4, o = j & 15;
        k1T[j] = (unsigned short)f2bf(k1[o * 64 + k]);
    } else if (i < 96 * 32 + 64 * 16 + 4 * 32) {
        int j = i - (3072 + 1024);
        int k = j >> 5, n = j & 31;
        float v = (k < 3) ? W1[n * 3 + k] : (b1[n] + bias1[n]);
        W1Tb[j] = (unsigned short)f2bf(v);
    }
}

// ---------------- Layer-2 MLP + conv1 via MFMA ------------------------------

__global__ __launch_bounds__(256) void k_mlp_mfma(
    const unsigned short* __restrict__ h1b,
    const unsigned short* __restrict__ hpb, const unsigned short* __restrict__ hnb,
    const unsigned short* __restrict__ W2sT, const unsigned short* __restrict__ k1T,
    const float* __restrict__ b2, const float* __restrict__ bias2,
    const float* __restrict__ bk1,
    float* __restrict__ y1) {
    __shared__ unsigned short h2s[4][16 * 32];     // per-wave transpose tile
    int t = threadIdx.x;
    int wv = t >> 6;
    int lane = t & 63;
    int col = lane & 15;
    int quad = lane >> 4;

    float bv0 = b2[col] + bias2[col];
    float bv1 = b2[col + 16] + bias2[col + 16];
    float bky = bk1[col];

    bf8 BW[2][3];
#pragma unroll
    for (int nt = 0; nt < 2; nt++)
#pragma unroll
        for (int kt = 0; kt < 3; kt++) {
            bf8 b;
#pragma unroll
            for (int j = 0; j < 8; j++)
                b[j] = (short)W2sT[(kt * 32 + quad * 8 + j) * 32 + nt * 16 + col];
            BW[nt][kt] = b;
        }
    bf8 BK[2];
#pragma unroll
    for (int kt = 0; kt < 2; kt++) {
        bf8 b;
#pragma unroll
        for (int j = 0; j < 8; j++)
            b[j] = (short)k1T[(kt * 32 + quad * 8 + j) * 16 + col];
        BK[kt] = b;
    }
    unsigned short* myT = h2s[wv];

#pragma unroll 1
    for (int g = 0; g < 4; g++) {
        int nbase = blockIdx.x * 256 + wv * 64 + g * 16;
        int node = nbase + col;                     // A-operand row m = col
        bf8 a0 = *(const bf8*)(h1b + (size_t)node * 32 + quad * 8);
        bf8 a1 = *(const bf8*)(hpb + (size_t)node * 32 + quad * 8);
        bf8 a2 = *(const bf8*)(hnb + (size_t)node * 32 + quad * 8);

        f4 acc0 = {bv0, bv0, bv0, bv0};
        f4 acc1 = {bv1, bv1, bv1, bv1};
        acc0 = __builtin_amdgcn_mfma_f32_16x16x32_bf16(a0, BW[0][0], acc0, 0, 0, 0);
        acc0 = __builtin_amdgcn_mfma_f32_16x16x32_bf16(a1, BW[0][1], acc0, 0, 0, 0);
        acc0 = __builtin_amdgcn_mfma_f32_16x16x32_bf16(a2, BW[0][2], acc0, 0, 0, 0);
        acc1 = __builtin_amdgcn_mfma_f32_16x16x32_bf16(a0, BW[1][0], acc1, 0, 0, 0);
        acc1 = __builtin_amdgcn_mfma_f32_16x16x32_bf16(a1, BW[1][1], acc1, 0, 0, 0);
        acc1 = __builtin_amdgcn_mfma_f32_16x16x32_bf16(a2, BW[1][2], acc1, 0, 0, 0);

#pragma unroll
        for (int i = 0; i < 4; i++) {
            int r = quad * 4 + i;
            myT[r * 32 + col]      = (unsigned short)f2bf(fmaxf(acc0[i], 0.f));
            myT[r * 32 + col + 16] = (unsigned short)f2bf(fmaxf(acc1[i], 0.f));
        }
        bf8 ah2 = *(const bf8*)(myT + col * 32 + quad * 8);

        f4 accy = {bky, bky, bky, bky};
        accy = __builtin_amdgcn_mfma_f32_16x16x32_bf16(a0,  BK[0], accy, 0, 0, 0);
        accy = __builtin_amdgcn_mfma_f32_16x16x32_bf16(ah2, BK[1], accy, 0, 0, 0);
#pragma unroll
        for (int i = 0; i < 4; i++)
            y1[(size_t)(nbase + quad * 4 + i) * 16 + col] = accy[i];
    }
}

// ---------------- Wfc repack: vec4-friendly layout for the head FC ----------
// W4[(c>>2)*512 + u*4 + (c&3)] = Wfc[u*416+c]: 4 consecutive input-terms
// contiguous per output -> FC reads one float4 per 4 terms, coalesced.

__global__ void k_transpose(const float* __restrict__ Wfc, float* __restrict__ W4) {
    int i = blockIdx.x * 256 + threadIdx.x;
    if (i < 128 * 416) {
        int u = i / 416, c = i - u * 416;
        W4[(c >> 2) * 512 + u * 4 + (c & 3)] = Wfc[i];
    }
}

// ---------------- Head: maxpool -> conv2 -> FC -> classifier -> log_softmax ----
// R13: FC W4 loads batched 8-deep (explicit load phase / fma phase split) with
// 4 rotating accumulators — keeps 8 L2 requests in flight instead of ~1 on the
// old single-acc chain (R12 showed VALUBusy 35%: latency-bound, not issue-bound).

__global__ __launch_bounds__(256) void k_head(
    const float* __restrict__ y1, const float* __restrict__ k2,
    const float* __restrict__ bk2, const float* __restrict__ W4,
    const float* __restrict__ bfc, const float* __restrict__ Wc,
    const float* __restrict__ bc, float* __restrict__ out) {
    __shared__ float yl[1296];       // 81 positions x 16 ch, [p][ch]
    __shared__ float zl[16][41];     // after maxpool, [ch][pos<40], pad
    __shared__ float xr[416];        // conv2 out, index oc*13+t
    __shared__ float k2s[1536];
    __shared__ float fl2[256];       // FC partials
    __shared__ float fl[128];
    __shared__ float ll[10];
    int t = threadIdx.x;
    int b = blockIdx.x;
    const float4* yb4 = (const float4*)(y1 + (size_t)b * 1296);
    for (int i = t; i < 324; i += 256) ((float4*)yl)[i] = yb4[i];
    for (int i = t; i < 1536; i += 256) k2s[i] = k2[i];
    __syncthreads();
    // maxpool over position pairs (drop pos 80)
    for (int i = t; i < 640; i += 256) {
        int ic = i & 15, p = i >> 4;
        zl[ic][p] = fmaxf(yl[(2 * p) * 16 + ic], yl[(2 * p + 1) * 16 + ic]);
    }
    __syncthreads();
    // conv2: 32 out-ch x 13 positions, stride 3, k=3
    for (int i = t; i < 416; i += 256) {
        int oc = i / 13, tt = i - oc * 13;
        float acc = bk2[oc];
        for (int ic = 0; ic < 16; ic++) {
            const float* kk = &k2s[(oc * 16 + ic) * 3];
            acc += zl[ic][3 * tt]     * kk[0]
                 + zl[ic][3 * tt + 1] * kk[1]
                 + zl[ic][3 * tt + 2] * kk[2];
        }
        xr[i] = acc;
    }
    __syncthreads();
    // FC 416 -> 128: 2 threads per output, 52 float4 chunks each.
    // 8-deep batched loads + 4 rotating accumulators (MLP + short fma chains).
    {
        int u = t & 127, q = t >> 7;
        const float4* xr4 = (const float4*)xr;
        const float* Wb = W4 + u * 4;
        float a0 = 0.f, a1 = 0.f, a2 = 0.f, a3 = 0.f;
        int base = q * 52;
#pragma unroll 1
        for (int b8 = 0; b8 < 6; b8++) {
            int c0 = base + b8 * 8;
            float4 wv[8], xv[8];
#pragma unroll
            for (int k = 0; k < 8; k++)
                wv[k] = *(const float4*)(Wb + (size_t)(c0 + k) * 512);
#pragma unroll
            for (int k = 0; k < 8; k++) xv[k] = xr4[c0 + k];
#pragma unroll
            for (int k = 0; k < 8; k++) {
                float s = fmaf(xv[k].x, wv[k].x,
                          fmaf(xv[k].y, wv[k].y,
                          fmaf(xv[k].z, wv[k].z, xv[k].w * wv[k].w)));
                if ((k & 3) == 0) a0 += s;
                else if ((k & 3) == 1) a1 += s;
                else if ((k & 3) == 2) a2 += s;
                else a3 += s;
            }
        }
        {   // tail: chunks 48..51
            int c0 = base + 48;
            float4 wv[4], xv[4];
#pragma unroll
            for (int k = 0; k < 4; k++)
                wv[k] = *(const float4*)(Wb + (size_t)(c0 + k) * 512);
#pragma unroll
            for (int k = 0; k < 4; k++) xv[k] = xr4[c0 + k];
#pragma unroll
            for (int k = 0; k < 4; k++) {
                float s = fmaf(xv[k].x, wv[k].x,
                          fmaf(xv[k].y, wv[k].y,
                          fmaf(xv[k].z, wv[k].z, xv[k].w * wv[k].w)));
                if (k == 0) a0 += s;
                else if (k == 1) a1 += s;
                else if (k == 2) a2 += s;
                else a3 += s;
            }
        }
        fl2[t] = (a0 + a1) + (a2 + a3);
    }
    __syncthreads();
    if (t < 128)
        fl[t] = fmaxf(fl2[t] + fl2[t + 128] + bfc[t], 0.f);
    __syncthreads();
    // classifier: 16 lanes per class, shfl reduce
    if (t < 160) {
        int c = t >> 4, l = t & 15;
        float acc = 0.f;
        for (int i = l * 8; i < l * 8 + 8; i++)
            acc += fl[i] * Wc[c * 128 + i];
        for (int m = 8; m; m >>= 1) acc += __shfl_down(acc, m, 16);
        if (l == 0) ll[c] = acc + bc[c];
    }
    __syncthreads();
    if (t < 10) {
        float m = -1e30f;
        for (int c = 0; c < 10; c++) m = fmaxf(m, ll[c]);
        float s = 0.f;
        for (int c = 0; c < 10; c++) s += __expf(ll[c] - m);
        out[b * 10 + t] = ll[t] - m - __logf(s);
    }
}

// ---------------- launch ----------------

extern "C" void kernel_launch(void* const* d_in, const int* in_sizes, int n_in,
                              void* d_out, int out_size, void* d_ws, size_t ws_size,
                              hipStream_t stream) {
    const int*   src   = (const int*)d_in[0];
    const int*   dst   = (const int*)d_in[1];
    const float* w     = (const float*)d_in[2];
    const float* W1    = (const float*)d_in[4];
    const float* b1    = (const float*)d_in[5];
    const float* bias1 = (const float*)d_in[6];
    const float* c1s   = (const float*)d_in[7];
    const float* c1p   = (const float*)d_in[8];
    const float* c1n   = (const float*)d_in[9];
    const float* W2    = (const float*)d_in[10];
    const float* b2    = (const float*)d_in[11];
    const float* bias2 = (const float*)d_in[12];
    const float* c2s   = (const float*)d_in[13];
    const float* c2p   = (const float*)d_in[14];
    const float* c2n   = (const float*)d_in[15];
    const float* k1    = (const float*)d_in[16];
    const float* bk1   = (const float*)d_in[17];
    const float* k2    = (const float*)d_in[18];
    const float* bk2   = (const float*)d_in[19];
    const float* Wfc   = (const float*)d_in[20];
    const float* bfc   = (const float*)d_in[21];
    const float* Wc    = (const float*)d_in[22];
    const float* bc    = (const float*)d_in[23];
    const int E = in_sizes[0];
    const int NT = (E + TE - 1) / TE;
    const int CS = (NT + CH - 1) / CH;

    // workspace carve (256B aligned) — xtab aliases y1 (read before y1 written)
    size_t off = 0;
    auto carve = [&](size_t bytes) -> char* {
        char* p = (char*)d_ws + off;
        off = (off + bytes + 255) & ~(size_t)255;
        return p;
    };
    int*   cnt    = (int*)  carve((size_t)NNODES * 4);
    int*   cntp   = (int*)  carve((size_t)NNODES * 4);
    int*   offs   = (int*)  carve((size_t)NNODES * 4);
    int2*  csrB   = (int2*) carve((size_t)E * 8);
    int*   H      = (int*)  carve((size_t)NT * NBUCK * 4);
    int*   P      = (int*)  carve((size_t)CH * NBUCK * 4);
    int*   T      = (int*)  carve((size_t)NBUCK * 4);
    int*   Bstart = (int*)  carve((size_t)(NBUCK + 1) * 4);
    float* spos   = (float*)carve((size_t)NNODES * 4);
    float* sneg   = (float*)carve((size_t)NNODES * 4);
    unsigned short* h1b = (unsigned short*)carve((size_t)NNODES * 32 * 2);
    unsigned short* hpb = (unsigned short*)carve((size_t)NNODES * 32 * 2);
    unsigned short* hnb = (unsigned short*)carve((size_t)NNODES * 32 * 2);
    float* y1     = (float*)carve((size_t)NNODES * 16 * 4);
    float* WfcT   = (float*)carve((size_t)128 * 416 * 4);
    unsigned short* W2sT = (unsigned short*)carve((size_t)96 * 32 * 2);
    unsigned short* k1T  = (unsigned short*)carve((size_t)64 * 16 * 2);
    unsigned short* W1Tb = (unsigned short*)carve((size_t)4 * 32 * 2);
    unsigned long long* xtab = (unsigned long long*)y1;  // alias: 2.65MB << y1
    (void)ws_size;

    k_hist      <<<NT, 256, 0, stream>>>(dst, H, E);
    k_colA      <<<CH * NBUCK / 256, 256, 0, stream>>>(H, P, NT, CS);
    k_colB      <<<NBUCK / 256, 256, 0, stream>>>(P, T);
    k_colC      <<<CH * NBUCK / 256, 256, 0, stream>>>(H, P, NT, CS);
    k_binscan   <<<1, 256, 0, stream>>>(T, Bstart);
    k_place     <<<NT, 1024, 0, stream>>>(src, dst, w, H, Bstart, csrB, E);
    k_sortbucket<<<NBUCK, 256, 0, stream>>>(csrB, Bstart, cnt, cntp, offs);
    k_layer1    <<<NNODES / 16, 256, 0, stream>>>(cnt, cntp, offs, csrB,
                                                  spos, sneg, h1b, xtab,
                                                  W1, b1, bias1, c1s, c1p, c1n);
    k_prep      <<<17, 256, 0, stream>>>(W2, c2s, c2p, c2n, k1,
                                         W1, b1, bias1, W2sT, k1T, W1Tb);
    k_transpose <<<(128 * 416 + 255) / 256, 256, 0, stream>>>(Wfc, WfcT);
    k_agg       <<<NNODES / 32, 256, 0, stream>>>(cnt, offs, csrB,
                                                  spos, sneg, xtab, W1Tb,
                                                  hpb, hnb, E);
    k_mlp_mfma  <<<NNODES / 256, 256, 0, stream>>>(h1b, hpb, hnb, W2sT, k1T,
                                                   b2, bias2, bk1, y1);
    k_head      <<<NGRAPH, 256, 0, stream>>>(y1, k2, bk2, WfcT, bfc, Wc, bc,
                                             (float*)d_out);
}

// Round 14
// 349.931 us; speedup vs baseline: 1.0195x; 1.0128x over previous
//
#include <hip/hip_runtime.h>
#include <hip/hip_bf16.h>

#define NNODES 331776            // 81 * 4096
#define NGRAPH 4096
#define NBUCK  2048              // buckets
#define BNODES 162               // nodes per bucket (2048*162 == 331776)
#define TE     16384             // edges per tile
#define PASSES 4                 // TE / (EB*256)   (k_hist only)
#define CAP    2560              // max edges/bucket (lambda=1953, 13.7 sigma)
#define CH     64                // tile-chunks for the 3-phase column scan
#define EB     16                // edges per thread per pass in k_hist
#define GH     8                 // graphs per block in k_head (weight reuse x8)

typedef __attribute__((ext_vector_type(8))) short bf8;   // 8 bf16 (4 VGPR)
typedef __attribute__((ext_vector_type(4))) float f4;    // 4 fp32 acc
typedef __attribute__((ext_vector_type(4))) unsigned int u32x4;

static __device__ __forceinline__ short f2bf(float x) {
    return (short)__builtin_bit_cast(unsigned short, __float2bfloat16(x));
}
static __device__ __forceinline__ float bf2f(unsigned short u) {
    return __bfloat162float(__hip_bfloat16_raw{u});
}

// ---------------- deterministic bucket sort (no global atomics) ----------------

__global__ __launch_bounds__(256) void k_hist(const int* __restrict__ dst,
                                              int* __restrict__ H, int E) {
    __shared__ int h[NBUCK];
    int t = threadIdx.x, b = blockIdx.x;
    for (int i = t; i < NBUCK; i += 256) h[i] = 0;
    __syncthreads();
    for (int pass = 0; pass < PASSES; pass++) {
        int lo = b * TE + pass * (EB * 256);
        int bins[EB]; bool ok[EB];
#pragma unroll
        for (int i = 0; i < EB; i++) {
            int e = lo + i * 256 + t;
            ok[i] = e < E;
            bins[i] = ok[i] ? (dst[e] / BNODES) : 0;
        }
#pragma unroll
        for (int i = 0; i < EB; i++)
            if (ok[i]) atomicAdd(&h[bins[i]], 1);
    }
    __syncthreads();
    for (int i = t; i < NBUCK; i += 256) H[b * NBUCK + i] = h[i];
}

// ---- 3-phase per-bin scan across tiles ----
__global__ __launch_bounds__(256) void k_colA(const int* __restrict__ H,
                                              int* __restrict__ P,
                                              int NT, int CS) {
    int idx = blockIdx.x * 256 + threadIdx.x;       // < CH*NBUCK
    int bin = idx & (NBUCK - 1);
    int chunk = idx >> 11;
    int t0 = chunk * CS, t1 = min(NT, t0 + CS);
    int s = 0;
    for (int t = t0; t < t1; t++) s += H[t * NBUCK + bin];
    P[chunk * NBUCK + bin] = s;
}

__global__ __launch_bounds__(256) void k_colB(int* __restrict__ P,
                                              int* __restrict__ T) {
    int bin = blockIdx.x * 256 + threadIdx.x;       // < NBUCK
    int s = 0;
    for (int c = 0; c < CH; c++) {
        int v = P[c * NBUCK + bin];
        P[c * NBUCK + bin] = s;
        s += v;
    }
    T[bin] = s;
}

__global__ __launch_bounds__(256) void k_colC(int* __restrict__ H,
                                              const int* __restrict__ P,
                                              int NT, int CS) {
    int idx = blockIdx.x * 256 + threadIdx.x;       // < CH*NBUCK
    int bin = idx & (NBUCK - 1);
    int chunk = idx >> 11;
    int t0 = chunk * CS, t1 = min(NT, t0 + CS);
    int s = P[chunk * NBUCK + bin];
    for (int t = t0; t < t1; t++) {
        int v = H[t * NBUCK + bin];
        H[t * NBUCK + bin] = s;
        s += v;
    }
}

// exclusive scan over the 2048 bucket totals -> Bstart[0..NBUCK]
__global__ __launch_bounds__(256) void k_binscan(const int* __restrict__ T,
                                                 int* __restrict__ Bstart) {
    __shared__ int tmp[256];
    int t = threadIdx.x;
    int base = t * 8;
    int loc[8]; int s = 0;
#pragma unroll
    for (int i = 0; i < 8; i++) { loc[i] = s; s += T[base + i]; }
    tmp[t] = s; __syncthreads();
    for (int o = 1; o < 256; o <<= 1) {
        int a = (t >= o) ? tmp[t - o] : 0;
        __syncthreads();
        tmp[t] += a;
        __syncthreads();
    }
    int excl = tmp[t] - s;
#pragma unroll
    for (int i = 0; i < 8; i++) Bstart[base + i] = excl + loc[i];
    if (t == 255) Bstart[NBUCK] = excl + s;
}

// place edges into bucket-major order; payload packs (src | dst_local<<19, es).
// R8: full-tile LDS staging -> linear readout so global writes are contiguous
// runs (~8 edges = 64B per bucket) -> line-granular write service.
__global__ __launch_bounds__(1024) void k_place(
    const int* __restrict__ src, const int* __restrict__ dst,
    const float* __restrict__ w,
    const int* __restrict__ H, const int* __restrict__ Bstart,
    int2* __restrict__ csrB, int E) {
    __shared__ int2 pb[TE];              // 128 KB sorted payload staging
    __shared__ int lstart[NBUCK + 1];    // local exclusive starts + sentinel
    __shared__ int gshift[NBUCK];        // global addr = gshift[bin] + i
    __shared__ int lcur[NBUCK];          // hist, then running cursor
    __shared__ int tsum[1024];           // scan temp
    int t = threadIdx.x, b = blockIdx.x;
    // phase 0+1: histogram
    for (int i = t; i < NBUCK; i += 1024) lcur[i] = 0;
    __syncthreads();
    {
        int bins[16];
#pragma unroll
        for (int k = 0; k < 16; k++) {
            int e = b * TE + k * 1024 + t;
            bins[k] = (e < E) ? (dst[e] / BNODES) : -1;
        }
#pragma unroll
        for (int k = 0; k < 16; k++)
            if (bins[k] >= 0) atomicAdd(&lcur[bins[k]], 1);
    }
    __syncthreads();
    // phase 2: 1024-wide scan over 2048 bins (2 bins/thread)
    int b0 = t * 2;
    int c0 = lcur[b0], c1 = lcur[b0 + 1];
    tsum[t] = c0 + c1;
    __syncthreads();
    for (int o = 1; o < 1024; o <<= 1) {
        int a = (t >= o) ? tsum[t - o] : 0;
        __syncthreads();
        tsum[t] += a;
        __syncthreads();
    }
    int excl = tsum[t] - (c0 + c1);
    lstart[b0] = excl;
    lstart[b0 + 1] = excl + c0;
    if (t == 1023) lstart[NBUCK] = excl + c0 + c1;   // S = edges in tile
    gshift[b0]     = Bstart[b0]     + H[b * NBUCK + b0]     - excl;
    gshift[b0 + 1] = Bstart[b0 + 1] + H[b * NBUCK + b0 + 1] - (excl + c0);
    lcur[b0] = excl;
    lcur[b0 + 1] = excl + c0;
    __syncthreads();
    // phase 3: place into LDS in bucket-sorted order
    {
        int dd[16], sx[16]; float wv[16]; bool ok[16];
#pragma unroll
        for (int k = 0; k < 16; k++) {
            int e = b * TE + k * 1024 + t;
            ok[k] = e < E;
            if (ok[k]) { dd[k] = dst[e]; sx[k] = src[e]; wv[k] = w[e]; }
        }
        int pk0[16]; float es[16]; int bin[16];
#pragma unroll
        for (int k = 0; k < 16; k++) {
            if (ok[k]) {
                float v = wv[k];
                float e2 = 0.f;
                if (v > 0.f)      e2 = __expf(v);
                else if (v < 0.f) e2 = -__expf(-v);
                es[k] = e2;
                bin[k] = dd[k] / BNODES;
                pk0[k] = sx[k] | ((dd[k] - bin[k] * BNODES) << 19);
            }
        }
        int p[16];
#pragma unroll
        for (int k = 0; k < 16; k++)
            if (ok[k]) p[k] = atomicAdd(&lcur[bin[k]], 1);
#pragma unroll
        for (int k = 0; k < 16; k++)
            if (ok[k]) {
                int2 pk; pk.x = pk0[k]; pk.y = __float_as_int(es[k]);
                pb[p[k]] = pk;
            }
    }
    __syncthreads();
    // phase 4: linear readout, coalesced global writes (runs per bucket)
    int S = lstart[NBUCK];
    for (int k = 0; k < 16; k++) {
        int i = k * 1024 + t;
        if (i < S) {
            int lo = 0, hi = NBUCK;                 // lstart[0]==0 <= i
            while (hi - lo > 1) {
                int mid = (lo + hi) >> 1;
                if (lstart[mid] <= i) lo = mid; else hi = mid;
            }
            csrB[gshift[lo] + i] = pb[i];
        }
    }
}

// per-bucket counting sort (in place), key = dst_local*2 + sign:
// each node's edges land [positives | negatives].
// Output payload: .x = src(19b) | (d&7)<<19 | sign<<22  (slot id for MFMA agg),
//                 .y = |es| fp32.
__global__ __launch_bounds__(256) void k_sortbucket(
    int2* __restrict__ csrB, const int* __restrict__ Bstart,
    int* __restrict__ cnt, int* __restrict__ cntp, int* __restrict__ offs) {
    __shared__ int2 pb[CAP];
    __shared__ int lcnt[BNODES * 2];
    __shared__ int lpos[BNODES * 2];
    int t = threadIdx.x, b = blockIdx.x;
    int lo = Bstart[b];
    int S  = Bstart[b + 1] - lo;
    if (S > CAP) S = CAP;                        // memory-safety guard
    for (int i = t; i < BNODES * 2; i += 256) lcnt[i] = 0;
    __syncthreads();
    for (int i = t; i < S; i += 256) {
        int2 pk = csrB[lo + i];                  // coalesced
        pb[i] = pk;
        int key = ((pk.x >> 19) << 1) | ((unsigned)pk.y >> 31);
        atomicAdd(&lcnt[key], 1);
    }
    __syncthreads();
    if (t == 0) {
        int s = 0;
        for (int i = 0; i < BNODES * 2; i++) { lpos[i] = s; s += lcnt[i]; }
    }
    __syncthreads();
    int node0 = b * BNODES;
    for (int i = t; i < BNODES; i += 256) {
        cnt[node0 + i]  = lcnt[2 * i] + lcnt[2 * i + 1];
        cntp[node0 + i] = lcnt[2 * i];
        offs[node0 + i] = lo + lpos[2 * i];
    }
    __syncthreads();
    for (int i = t; i < S; i += 256) {
        int2 pk = pb[i];
        int local = pk.x >> 19;
        int sign  = (unsigned)pk.y >> 31;
        int key = (local << 1) | sign;
        int p = atomicAdd(&lpos[key], 1);
        int d7 = (node0 + local) & 7;            // node mod 8 -> slot id bits
        int2 outv;
        outv.x = (pk.x & 0x7FFFF) | (d7 << 19) | (sign << 22);
        outv.y = pk.y & 0x7FFFFFFF;              // |es|
        csrB[lo + p] = outv;                     // bucket-local, L2-hot
    }
}

// ---------------- Layer 1 (h0 = deg, 1 feature -> 32), bf16 output ----------
// 16 lanes/node; epilogue computes 2 features per lane (f, f+16).
// Emits xtab[d] = bf16x4 (c1s*deg, c1p*hp, c1n*hn, 1.0) — the MFMA-agg A operand.

__global__ __launch_bounds__(256) void k_layer1(
    const int* __restrict__ cnt, const int* __restrict__ cntp,
    const int* __restrict__ offs, const int2* __restrict__ csr,
    float* __restrict__ spos, float* __restrict__ sneg,
    unsigned short* __restrict__ h1b,
    unsigned long long* __restrict__ xtab,
    const float* __restrict__ W1, const float* __restrict__ b1,
    const float* __restrict__ bias1,
    const float* __restrict__ c1s, const float* __restrict__ c1p,
    const float* __restrict__ c1n) {
    int t = threadIdx.x;
    int g = t >> 4, f = t & 15;           // 16 groups x 16 lanes
    int d = blockIdx.x * 16 + g;          // NNODES % 16 == 0
    int beg = offs[d];
    int len = cnt[d];
    int np  = cntp[d];
    float sp = 0.f, sn = 0.f, up = 0.f, un = 0.f;
    for (int j = 0; j < len; j += 16) {
        int rem = len - j;
        if (f < rem) {
            int2 sw = csr[beg + j + f];            // coalesced 8B/lane
            float es = __int_as_float(sw.y);        // |es|
            float degs = (float)cnt[sw.x & 0x7FFFF]; // mask slot bits
            float ep = (j + f < np) ? es : 0.f;
            float en = es - ep;
            sp += ep; sn += en;
            up = fmaf(degs, ep, up); un = fmaf(degs, en, un);
        }
    }
#pragma unroll
    for (int m = 8; m; m >>= 1) {
        sp += __shfl_xor(sp, m, 16);
        sn += __shfl_xor(sn, m, 16);
        up += __shfl_xor(up, m, 16);
        un += __shfl_xor(un, m, 16);
    }
    if (f == 0) { spos[d] = sp; sneg[d] = sn; }
    float hp = up / fmaxf(sp, 1e-20f);
    float hn = un / fmaxf(sn, 1e-20f);
    float x0 = c1s[0] * (float)len;   // deg[d] == len
    float x1 = c1p[0] * hp;
    float x2 = c1n[0] * hn;
    if (f == 0) {
        unsigned long long u0 = (unsigned short)f2bf(x0);
        unsigned long long u1 = (unsigned short)f2bf(x1);
        unsigned long long u2 = (unsigned short)f2bf(x2);
        xtab[d] = u0 | (u1 << 16) | (u2 << 32) | (0x3F80ULL << 48); // +1.0
    }
#pragma unroll
    for (int q = 0; q < 2; q++) {
        int ff = f + q * 16;
        float v = W1[ff * 3] * x0 + W1[ff * 3 + 1] * x1 + W1[ff * 3 + 2] * x2
                + b1[ff] + bias1[ff];
        v = fmaxf(v, 0.f);
        h1b[d * 32 + ff] = (unsigned short)f2bf(v);  // bf16 table (MFMA A operand)
    }
}

// ---------------- Layer-2 aggregation via MFMA --------------------------------
// Per wave: 8 nodes = 16 slots (node&7 x sign). Window = 32 edges.
//  MFMA1 (x4): H[edge16][feat16] = relu(Xe * W1T), bias folded via x3=1.
//  MFMA2 (x2): OUT[slot16][feat16] += S * H, S one-hot per edge column.
// R11: 3-stage software pipeline — load rec[w+2] || derive+gather w+1 ||
// compute w. Hides the ~500cy csr->bpermute->xtab front chain of windows
// 1..nw-1 under window w's MFMA+LDS work (only acc2 carries a dependency).

struct AggFront {
    int pk;                       // es16 | slot<<16
    unsigned long long r80, r81;  // xtab records for eh=0,1 (quad0 lanes)
};

__global__ __launch_bounds__(256) void k_agg(
    const int* __restrict__ cnt, const int* __restrict__ offs,
    const int2* __restrict__ csr,
    const float* __restrict__ spos, const float* __restrict__ sneg,
    const unsigned long long* __restrict__ xtab,
    const unsigned short* __restrict__ W1Tb,   // [4][32] bf16, row3 = b1+bias1
    unsigned short* __restrict__ hpb, unsigned short* __restrict__ hnb,
    int E) {
    __shared__ unsigned short Hl[4][32][40];   // [wave][feat][edge], stride 80B
    __shared__ unsigned short Sl[4][16][40];   // [wave][slot][edge], stride 80B
    int t = threadIdx.x;
    int wv = t >> 6, lane = t & 63;
    int col = lane & 15, quad = lane >> 4;
    int d0 = (blockIdx.x * 4 + wv) * 8;
    int beg = offs[d0];
    int totlen = 0;
#pragma unroll
    for (int i = 0; i < 8; i++) totlen += cnt[d0 + i];

    // B1 = W1T fragments (feat halves); only quad 0 (k=0..7, j<4) nonzero
    bf8 B1[2];
#pragma unroll
    for (int fh = 0; fh < 2; fh++) {
        u32x4 bw = {0u, 0u, 0u, 0u};
        if (quad == 0) {
            int n = fh * 16 + col;
            unsigned w0 = W1Tb[0 * 32 + n], w1 = W1Tb[1 * 32 + n];
            unsigned w2 = W1Tb[2 * 32 + n], w3 = W1Tb[3 * 32 + n];
            bw.x = w0 | (w1 << 16);
            bw.y = w2 | (w3 << 16);
        }
        B1[fh] = __builtin_bit_cast(bf8, bw);
    }

    f4 acc2[2] = {{0.f, 0.f, 0.f, 0.f}, {0.f, 0.f, 0.f, 0.f}};
    unsigned short (*myH)[40] = Hl[wv];
    unsigned short (*myS)[40] = Sl[wv];
    int nw = (totlen + 31) >> 5;

    // stage helpers (lambdas keep the register state explicit)
    auto LDREC = [&](int w) -> long long {
        int eidx = w * 32 + (lane & 31);
        int gidx = beg + ((eidx < totlen) ? eidx : 0);
        gidx = gidx < E ? gidx : E - 1;            // guard (empty-group case)
        return *(const long long*)(csr + gidx);    // halves duplicate
    };
    auto DERIVE = [&](long long rec, int w, AggFront& f) {
        int x = (int)rec;
        float ef = __int_as_float((int)(rec >> 32));   // |es|
        int eidx = w * 32 + (lane & 31);
        int slot = (eidx < totlen) ? (((x >> 19) & 7) * 2 + ((x >> 22) & 1)) : 255;
        unsigned es16 = (unsigned)(unsigned short)f2bf(ef);
        f.pk = (int)(es16 | ((unsigned)slot << 16));
        int xm0 = __builtin_amdgcn_ds_bpermute(col * 4, x);
        int xm1 = __builtin_amdgcn_ds_bpermute((16 + col) * 4, x);
        f.r80 = 0; f.r81 = 0;
        if (quad == 0) {
            f.r80 = xtab[(unsigned)xm0 & 0x7FFFF];     // exec-masked gathers
            f.r81 = xtab[(unsigned)xm1 & 0x7FFFF];
        }
    };

    if (nw > 0) {
        AggFront fc, fn;
        long long rec0 = LDREC(0);
        DERIVE(rec0, 0, fc);
        long long recN = (nw > 1) ? LDREC(1) : rec0;

        for (int w = 0; w < nw; w++) {
            // stage: issue next-next record load + next window's derive/gather
            long long recNN = (w + 2 < nw) ? LDREC(w + 2) : recN;
            if (w + 1 < nw) DERIVE(recN, w + 1, fn);
            recN = recNN;

            // ---- compute window w from fc ----
            int slot = ((unsigned)fc.pk >> 16);
            unsigned short es16 = (unsigned short)(fc.pk & 0xFFFF);
            {
                u32x4 z = {0u, 0u, 0u, 0u};
                *(u32x4*)&myS[lane >> 2][(lane & 3) * 8] = z;
            }
            if (lane < 32 && slot < 16)
                myS[slot][lane & 31] = es16;

            // MFMA1: H = relu(Xe * W1T) for both 16-edge halves
#pragma unroll
            for (int eh = 0; eh < 2; eh++) {
                unsigned long long r8 = eh ? fc.r81 : fc.r80;
                u32x4 av = {(unsigned)r8, (unsigned)(r8 >> 32), 0u, 0u};
                bf8 A1 = __builtin_bit_cast(bf8, av);
#pragma unroll
                for (int fh = 0; fh < 2; fh++) {
                    f4 h = {0.f, 0.f, 0.f, 0.f};
                    h = __builtin_amdgcn_mfma_f32_16x16x32_bf16(A1, B1[fh], h, 0, 0, 0);
                    float l0 = fmaxf(h[0], 0.f), h0 = fmaxf(h[1], 0.f);
                    float l1 = fmaxf(h[2], 0.f), h1 = fmaxf(h[3], 0.f);
                    unsigned u0, u1;
                    asm("v_cvt_pk_bf16_f32 %0, %1, %2" : "=v"(u0) : "v"(l0), "v"(h0));
                    asm("v_cvt_pk_bf16_f32 %0, %1, %2" : "=v"(u1) : "v"(l1), "v"(h1));
                    *(unsigned long long*)&myH[fh * 16 + col][eh * 16 + quad * 4] =
                        (unsigned long long)u0 | ((unsigned long long)u1 << 32);
                }
            }

            // A2 = S[col][quad*8..+8] (one 16B LDS read)
            bf8 A2 = *(const bf8*)&myS[col][quad * 8];

            // MFMA2: acc += S * H
#pragma unroll
            for (int fh = 0; fh < 2; fh++) {
                bf8 B2 = *(const bf8*)&myH[fh * 16 + col][quad * 8];
                acc2[fh] = __builtin_amdgcn_mfma_f32_16x16x32_bf16(A2, B2, acc2[fh], 0, 0, 0);
            }
            fc = fn;                    // rotate (garbage on last iter, unused)
        }
    }

    // ---- epilogue: normalize per slot, store bf16 ----
#pragma unroll
    for (int i = 0; i < 4; i++) {
        int slot = quad * 4 + i;
        int node = d0 + (slot >> 1);
        float s = (slot & 1) ? sneg[node] : spos[node];
        float r = 1.0f / fmaxf(s, 1e-20f);
        unsigned short* bp = (slot & 1) ? hnb : hpb;
#pragma unroll
        for (int fh = 0; fh < 2; fh++) {
            float v = acc2[fh][i] * r;
            bp[(size_t)node * 32 + fh * 16 + col] = (unsigned short)f2bf(v);
        }
    }
}

// ---------------- weight prep: bf16 transposed, scales folded ---------------

__global__ __launch_bounds__(256) void k_prep(
    const float* __restrict__ W2, const float* __restrict__ c2s,
    const float* __restrict__ c2p, const float* __restrict__ c2n,
    const float* __restrict__ k1,
    const float* __restrict__ W1, const float* __restrict__ b1,
    const float* __restrict__ bias1,
    unsigned short* __restrict__ W2sT, unsigned short* __restrict__ k1T,
    unsigned short* __restrict__ W1Tb) {
    int i = blockIdx.x * 256 + threadIdx.x;
    if (i < 96 * 32) {
        int k = i >> 5, n = i & 31;
        float sc = (k < 32) ? c2s[0] : ((k < 64) ? c2p[0] : c2n[0]);
        W2sT[i] = (unsigned short)f2bf(W2[n * 96 + k] * sc);
    } else if (i < 96 * 32 + 64 * 16) {
        int j = i - 3072;
        int k = j >> 4, o = j & 15;
        k1T[j] = (unsigned short)f2bf(k1[o * 64 + k]);
    } else if (i < 96 * 32 + 64 * 16 + 4 * 32) {
        int j = i - (3072 + 1024);
        int k = j >> 5, n = j & 31;
        float v = (k < 3) ? W1[n * 3 + k] : (b1[n] + bias1[n]);
        W1Tb[j] = (unsigned short)f2bf(v);
    }
}

// ---------------- Layer-2 MLP + conv1 via MFMA ------------------------------

__global__ __launch_bounds__(256) void k_mlp_mfma(
    const unsigned short* __restrict__ h1b,
    const unsigned short* __restrict__ hpb, const unsigned short* __restrict__ hnb,
    const unsigned short* __restrict__ W2sT, const unsigned short* __restrict__ k1T,
    const float* __restrict__ b2, const float* __restrict__ bias2,
    const float* __restrict__ bk1,
    float* __restrict__ y1) {
    __shared__ unsigned short h2s[4][16 * 32];     // per-wave transpose tile
    int t = threadIdx.x;
    int wv = t >> 6;
    int lane = t & 63;
    int col = lane & 15;
    int quad = lane >> 4;

    float bv0 = b2[col] + bias2[col];
    float bv1 = b2[col + 16] + bias2[col + 16];
    float bky = bk1[col];

    bf8 BW[2][3];
#pragma unroll
    for (int nt = 0; nt < 2; nt++)
#pragma unroll
        for (int kt = 0; kt < 3; kt++) {
            bf8 b;
#pragma unroll
            for (int j = 0; j < 8; j++)
                b[j] = (short)W2sT[(kt * 32 + quad * 8 + j) * 32 + nt * 16 + col];
            BW[nt][kt] = b;
        }
    bf8 BK[2];
#pragma unroll
    for (int kt = 0; kt < 2; kt++) {
        bf8 b;
#pragma unroll
        for (int j = 0; j < 8; j++)
            b[j] = (short)k1T[(kt * 32 + quad * 8 + j) * 16 + col];
        BK[kt] = b;
    }
    unsigned short* myT = h2s[wv];

#pragma unroll 1
    for (int g = 0; g < 4; g++) {
        int nbase = blockIdx.x * 256 + wv * 64 + g * 16;
        int node = nbase + col;                     // A-operand row m = col
        bf8 a0 = *(const bf8*)(h1b + (size_t)node * 32 + quad * 8);
        bf8 a1 = *(const bf8*)(hpb + (size_t)node * 32 + quad * 8);
        bf8 a2 = *(const bf8*)(hnb + (size_t)node * 32 + quad * 8);

        f4 acc0 = {bv0, bv0, bv0, bv0};
        f4 acc1 = {bv1, bv1, bv1, bv1};
        acc0 = __builtin_amdgcn_mfma_f32_16x16x32_bf16(a0, BW[0][0], acc0, 0, 0, 0);
        acc0 = __builtin_amdgcn_mfma_f32_16x16x32_bf16(a1, BW[0][1], acc0, 0, 0, 0);
        acc0 = __builtin_amdgcn_mfma_f32_16x16x32_bf16(a2, BW[0][2], acc0, 0, 0, 0);
        acc1 = __builtin_amdgcn_mfma_f32_16x16x32_bf16(a0, BW[1][0], acc1, 0, 0, 0);
        acc1 = __builtin_amdgcn_mfma_f32_16x16x32_bf16(a1, BW[1][1], acc1, 0, 0, 0);
        acc1 = __builtin_amdgcn_mfma_f32_16x16x32_bf16(a2, BW[1][2], acc1, 0, 0, 0);

#pragma unroll
        for (int i = 0; i < 4; i++) {
            int r = quad * 4 + i;
            myT[r * 32 + col]      = (unsigned short)f2bf(fmaxf(acc0[i], 0.f));
            myT[r * 32 + col + 16] = (unsigned short)f2bf(fmaxf(acc1[i], 0.f));
        }
        bf8 ah2 = *(const bf8*)(myT + col * 32 + quad * 8);

        f4 accy = {bky, bky, bky, bky};
        accy = __builtin_amdgcn_mfma_f32_16x16x32_bf16(a0,  BK[0], accy, 0, 0, 0);
        accy = __builtin_amdgcn_mfma_f32_16x16x32_bf16(ah2, BK[1], accy, 0, 0, 0);
#pragma unroll
        for (int i = 0; i < 4; i++)
            y1[(size_t)(nbase + quad * 4 + i) * 16 + col] = accy[i];
    }
}

// ---------------- Wfc repack: vec4-friendly layout for the head FC ----------
// W4[(c>>2)*512 + u*4 + (c&3)] = Wfc[u*416+c]: 4 consecutive input-terms
// contiguous per output -> FC reads one float4 per 4 terms, coalesced.

__global__ void k_transpose(const float* __restrict__ Wfc, float* __restrict__ W4) {
    int i = blockIdx.x * 256 + threadIdx.x;
    if (i < 128 * 416) {
        int u = i / 416, c = i - u * 416;
        W4[(c >> 2) * 512 + u * 4 + (c & 3)] = Wfc[i];
    }
}

// ---------------- Head: maxpool -> conv2 -> FC -> classifier -> log_softmax ----
// R14: GH=8 graphs per block (grid 512). Conv front-end per graph into
// xr_all[8][416]; the FC loads each W4 float4 ONCE and applies it to all 8
// graphs (8 independent accumulators). Weight L2 traffic drops 8x (850->106MB)
// and the 8 fma-chains per load give MLP without extra batching.

__global__ __launch_bounds__(256) void k_head(
    const float* __restrict__ y1, const float* __restrict__ k2,
    const float* __restrict__ bk2, const float* __restrict__ W4,
    const float* __restrict__ bfc, const float* __restrict__ Wc,
    const float* __restrict__ bc, float* __restrict__ out) {
    __shared__ float yl[1296];          // 81 positions x 16 ch
    __shared__ float zl[16][41];        // after maxpool, pad
    __shared__ float k2s[1536];
    __shared__ float xr_all[GH][416];   // conv2 out per graph
    __shared__ float fl2s[2][128 * GH]; // FC half-partials [q][u*GH+g]
    __shared__ float fl_all[GH][128];
    __shared__ float ll[GH][10];
    int t = threadIdx.x;
    int b0 = blockIdx.x * GH;
    for (int i = t; i < 1536; i += 256) k2s[i] = k2[i];
    // conv front-end, one graph at a time (yl/zl reused)
    for (int g = 0; g < GH; g++) {
        const float4* yb4 = (const float4*)(y1 + (size_t)(b0 + g) * 1296);
        __syncthreads();
        for (int i = t; i < 324; i += 256) ((float4*)yl)[i] = yb4[i];
        __syncthreads();
        for (int i = t; i < 640; i += 256) {
            int ic = i & 15, p = i >> 4;
            zl[ic][p] = fmaxf(yl[(2 * p) * 16 + ic], yl[(2 * p + 1) * 16 + ic]);
        }
        __syncthreads();
        for (int i = t; i < 416; i += 256) {
            int oc = i / 13, tt = i - oc * 13;
            float acc = bk2[oc];
            for (int ic = 0; ic < 16; ic++) {
                const float* kk = &k2s[(oc * 16 + ic) * 3];
                acc += zl[ic][3 * tt]     * kk[0]
                     + zl[ic][3 * tt + 1] * kk[1]
                     + zl[ic][3 * tt + 2] * kk[2];
            }
            xr_all[g][i] = acc;
        }
    }
    __syncthreads();
    // FC 416 -> 128: 2 threads per output u, 52 chunks each; weight float4
    // loaded once, reused across GH graphs.
    {
        int u = t & 127, q = t >> 7;
        const float* Wb = W4 + u * 4;
        float acc[GH];
#pragma unroll
        for (int g = 0; g < GH; g++) acc[g] = 0.f;
        int base = q * 52;
#pragma unroll 2
        for (int i4 = base; i4 < base + 52; i4++) {
            float4 wv = *(const float4*)(Wb + (size_t)i4 * 512);
#pragma unroll
            for (int g = 0; g < GH; g++) {
                float4 xv = *(const float4*)&xr_all[g][i4 * 4];  // broadcast read
                acc[g] = fmaf(xv.x, wv.x,
                         fmaf(xv.y, wv.y,
                         fmaf(xv.z, wv.z, fmaf(xv.w, wv.w, acc[g]))));
            }
        }
#pragma unroll
        for (int g = 0; g < GH; g++) fl2s[q][u * GH + g] = acc[g];
    }
    __syncthreads();
    if (t < 128) {
        float bv = bfc[t];
#pragma unroll
        for (int g = 0; g < GH; g++)
            fl_all[g][t] = fmaxf(fl2s[0][t * GH + g] + fl2s[1][t * GH + g] + bv, 0.f);
    }
    __syncthreads();
    // classifier: 16 lanes per class, shfl reduce, looped over graphs
    if (t < 160) {
        int c = t >> 4, l = t & 15;
        for (int g = 0; g < GH; g++) {
            float acc = 0.f;
            const float* fl = fl_all[g];
            for (int i = l * 8; i < l * 8 + 8; i++)
                acc += fl[i] * Wc[c * 128 + i];
            for (int m = 8; m; m >>= 1) acc += __shfl_down(acc, m, 16);
            if (l == 0) ll[g][c] = acc + bc[c];
        }
    }
    __syncthreads();
    if (t < GH * 10) {
        int g = t / 10, c = t - g * 10;
        const float* lg = ll[g];
        float m = -1e30f;
        for (int k = 0; k < 10; k++) m = fmaxf(m, lg[k]);
        float s = 0.f;
        for (int k = 0; k < 10; k++) s += __expf(lg[k] - m);
        out[(b0 + g) * 10 + c] = lg[c] - m - __logf(s);
    }
}

// ---------------- launch ----------------

extern "C" void kernel_launch(void* const* d_in, const int* in_sizes, int n_in,
                              void* d_out, int out_size, void* d_ws, size_t ws_size,
                              hipStream_t stream) {
    const int*   src   = (const int*)d_in[0];
    const int*   dst   = (const int*)d_in[1];
    const float* w     = (const float*)d_in[2];
    const float* W1    = (const float*)d_in[4];
    const float* b1    = (const float*)d_in[5];
    const float* bias1 = (const float*)d_in[6];
    const float* c1s   = (const float*)d_in[7];
    const float* c1p   = (const float*)d_in[8];
    const float* c1n   = (const float*)d_in[9];
    const float* W2    = (const float*)d_in[10];
    const float* b2    = (const float*)d_in[11];
    const float* bias2 = (const float*)d_in[12];
    const float* c2s   = (const float*)d_in[13];
    const float* c2p   = (const float*)d_in[14];
    const float* c2n   = (const float*)d_in[15];
    const float* k1    = (const float*)d_in[16];
    const float* bk1   = (const float*)d_in[17];
    const float* k2    = (const float*)d_in[18];
    const float* bk2   = (const float*)d_in[19];
    const float* Wfc   = (const float*)d_in[20];
    const float* bfc   = (const float*)d_in[21];
    const float* Wc    = (const float*)d_in[22];
    const float* bc    = (const float*)d_in[23];
    const int E = in_sizes[0];
    const int NT = (E + TE - 1) / TE;
    const int CS = (NT + CH - 1) / CH;

    // workspace carve (256B aligned) — xtab aliases y1 (read before y1 written)
    size_t off = 0;
    auto carve = [&](size_t bytes) -> char* {
        char* p = (char*)d_ws + off;
        off = (off + bytes + 255) & ~(size_t)255;
        return p;
    };
    int*   cnt    = (int*)  carve((size_t)NNODES * 4);
    int*   cntp   = (int*)  carve((size_t)NNODES * 4);
    int*   offs   = (int*)  carve((size_t)NNODES * 4);
    int2*  csrB   = (int2*) carve((size_t)E * 8);
    int*   H      = (int*)  carve((size_t)NT * NBUCK * 4);
    int*   P      = (int*)  carve((size_t)CH * NBUCK * 4);
    int*   T      = (int*)  carve((size_t)NBUCK * 4);
    int*   Bstart = (int*)  carve((size_t)(NBUCK + 1) * 4);
    float* spos   = (float*)carve((size_t)NNODES * 4);
    float* sneg   = (float*)carve((size_t)NNODES * 4);
    unsigned short* h1b = (unsigned short*)carve((size_t)NNODES * 32 * 2);
    unsigned short* hpb = (unsigned short*)carve((size_t)NNODES * 32 * 2);
    unsigned short* hnb = (unsigned short*)carve((size_t)NNODES * 32 * 2);
    float* y1     = (float*)carve((size_t)NNODES * 16 * 4);
    float* WfcT   = (float*)carve((size_t)128 * 416 * 4);
    unsigned short* W2sT = (unsigned short*)carve((size_t)96 * 32 * 2);
    unsigned short* k1T  = (unsigned short*)carve((size_t)64 * 16 * 2);
    unsigned short* W1Tb = (unsigned short*)carve((size_t)4 * 32 * 2);
    unsigned long long* xtab = (unsigned long long*)y1;  // alias: 2.65MB << y1
    (void)ws_size;

    k_hist      <<<NT, 256, 0, stream>>>(dst, H, E);
    k_colA      <<<CH * NBUCK / 256, 256, 0, stream>>>(H, P, NT, CS);
    k_colB      <<<NBUCK / 256, 256, 0, stream>>>(P, T);
    k_colC      <<<CH * NBUCK / 256, 256, 0, stream>>>(H, P, NT, CS);
    k_binscan   <<<1, 256, 0, stream>>>(T, Bstart);
    k_place     <<<NT, 1024, 0, stream>>>(src, dst, w, H, Bstart, csrB, E);
    k_sortbucket<<<NBUCK, 256, 0, stream>>>(csrB, Bstart, cnt, cntp, offs);
    k_layer1    <<<NNODES / 16, 256, 0, stream>>>(cnt, cntp, offs, csrB,
                                                  spos, sneg, h1b, xtab,
                                                  W1, b1, bias1, c1s, c1p, c1n);
    k_prep      <<<17, 256, 0, stream>>>(W2, c2s, c2p, c2n, k1,
                                         W1, b1, bias1, W2sT, k1T, W1Tb);
    k_transpose <<<(128 * 416 + 255) / 256, 256, 0, stream>>>(Wfc, WfcT);
    k_agg       <<<NNODES / 32, 256, 0, stream>>>(cnt, offs, csrB,
                                                  spos, sneg, xtab, W1Tb,
                                                  hpb, hnb, E);
    k_mlp_mfma  <<<NNODES / 256, 256, 0, stream>>>(h1b, hpb, hnb, W2sT, k1T,
                                                   b2, bias2, bk1, y1);
    k_head      <<<NGRAPH / GH, 256, 0, stream>>>(y1, k2, bk2, WfcT, bfc, Wc, bc,
                                                  (float*)d_out);
}

// Round 15
// 346.656 us; speedup vs baseline: 1.0291x; 1.0094x over previous
//
#include <hip/hip_runtime.h>
#include <hip/hip_bf16.h>

#define NNODES 331776            // 81 * 4096
#define NGRAPH 4096
#define NBUCK  2048              // buckets
#define BNODES 162               // nodes per bucket (2048*162 == 331776)
#define TE     16384             // edges per tile
#define PASSES 4                 // TE / (EB*256)   (k_hist only)
#define CAP    2560              // max edges/bucket (lambda=1953, 13.7 sigma)
#define CH     64                // tile-chunks for the 3-phase column scan
#define EB     16                // edges per thread per pass in k_hist
#define GH     8                 // graphs per block in k_head (weight reuse x8)

typedef __attribute__((ext_vector_type(8))) short bf8;   // 8 bf16 (4 VGPR)
typedef __attribute__((ext_vector_type(4))) float f4;    // 4 fp32 acc
typedef __attribute__((ext_vector_type(16))) float f16x; // 32x32 MFMA acc
typedef __attribute__((ext_vector_type(4))) unsigned int u32x4;

static __device__ __forceinline__ short f2bf(float x) {
    return (short)__builtin_bit_cast(unsigned short, __float2bfloat16(x));
}
static __device__ __forceinline__ float bf2f(unsigned short u) {
    return __bfloat162float(__hip_bfloat16_raw{u});
}

// ---------------- deterministic bucket sort (no global atomics) ----------------

__global__ __launch_bounds__(256) void k_hist(const int* __restrict__ dst,
                                              int* __restrict__ H, int E) {
    __shared__ int h[NBUCK];
    int t = threadIdx.x, b = blockIdx.x;
    for (int i = t; i < NBUCK; i += 256) h[i] = 0;
    __syncthreads();
    for (int pass = 0; pass < PASSES; pass++) {
        int lo = b * TE + pass * (EB * 256);
        int bins[EB]; bool ok[EB];
#pragma unroll
        for (int i = 0; i < EB; i++) {
            int e = lo + i * 256 + t;
            ok[i] = e < E;
            bins[i] = ok[i] ? (dst[e] / BNODES) : 0;
        }
#pragma unroll
        for (int i = 0; i < EB; i++)
            if (ok[i]) atomicAdd(&h[bins[i]], 1);
    }
    __syncthreads();
    for (int i = t; i < NBUCK; i += 256) H[b * NBUCK + i] = h[i];
}

// ---- 3-phase per-bin scan across tiles ----
__global__ __launch_bounds__(256) void k_colA(const int* __restrict__ H,
                                              int* __restrict__ P,
                                              int NT, int CS) {
    int idx = blockIdx.x * 256 + threadIdx.x;       // < CH*NBUCK
    int bin = idx & (NBUCK - 1);
    int chunk = idx >> 11;
    int t0 = chunk * CS, t1 = min(NT, t0 + CS);
    int s = 0;
    for (int t = t0; t < t1; t++) s += H[t * NBUCK + bin];
    P[chunk * NBUCK + bin] = s;
}

__global__ __launch_bounds__(256) void k_colB(int* __restrict__ P,
                                              int* __restrict__ T) {
    int bin = blockIdx.x * 256 + threadIdx.x;       // < NBUCK
    int s = 0;
    for (int c = 0; c < CH; c++) {
        int v = P[c * NBUCK + bin];
        P[c * NBUCK + bin] = s;
        s += v;
    }
    T[bin] = s;
}

__global__ __launch_bounds__(256) void k_colC(int* __restrict__ H,
                                              const int* __restrict__ P,
                                              int NT, int CS) {
    int idx = blockIdx.x * 256 + threadIdx.x;       // < CH*NBUCK
    int bin = idx & (NBUCK - 1);
    int chunk = idx >> 11;
    int t0 = chunk * CS, t1 = min(NT, t0 + CS);
    int s = P[chunk * NBUCK + bin];
    for (int t = t0; t < t1; t++) {
        int v = H[t * NBUCK + bin];
        H[t * NBUCK + bin] = s;
        s += v;
    }
}

// exclusive scan over the 2048 bucket totals -> Bstart[0..NBUCK]
__global__ __launch_bounds__(256) void k_binscan(const int* __restrict__ T,
                                                 int* __restrict__ Bstart) {
    __shared__ int tmp[256];
    int t = threadIdx.x;
    int base = t * 8;
    int loc[8]; int s = 0;
#pragma unroll
    for (int i = 0; i < 8; i++) { loc[i] = s; s += T[base + i]; }
    tmp[t] = s; __syncthreads();
    for (int o = 1; o < 256; o <<= 1) {
        int a = (t >= o) ? tmp[t - o] : 0;
        __syncthreads();
        tmp[t] += a;
        __syncthreads();
    }
    int excl = tmp[t] - s;
#pragma unroll
    for (int i = 0; i < 8; i++) Bstart[base + i] = excl + loc[i];
    if (t == 255) Bstart[NBUCK] = excl + s;
}

// place edges into bucket-major order; payload packs (src | dst_local<<19, es).
// R8: full-tile LDS staging -> linear readout so global writes are contiguous
// runs (~8 edges = 64B per bucket) -> line-granular write service.
__global__ __launch_bounds__(1024) void k_place(
    const int* __restrict__ src, const int* __restrict__ dst,
    const float* __restrict__ w,
    const int* __restrict__ H, const int* __restrict__ Bstart,
    int2* __restrict__ csrB, int E) {
    __shared__ int2 pb[TE];              // 128 KB sorted payload staging
    __shared__ int lstart[NBUCK + 1];    // local exclusive starts + sentinel
    __shared__ int gshift[NBUCK];        // global addr = gshift[bin] + i
    __shared__ int lcur[NBUCK];          // hist, then running cursor
    __shared__ int tsum[1024];           // scan temp
    int t = threadIdx.x, b = blockIdx.x;
    // phase 0+1: histogram
    for (int i = t; i < NBUCK; i += 1024) lcur[i] = 0;
    __syncthreads();
    {
        int bins[16];
#pragma unroll
        for (int k = 0; k < 16; k++) {
            int e = b * TE + k * 1024 + t;
            bins[k] = (e < E) ? (dst[e] / BNODES) : -1;
        }
#pragma unroll
        for (int k = 0; k < 16; k++)
            if (bins[k] >= 0) atomicAdd(&lcur[bins[k]], 1);
    }
    __syncthreads();
    // phase 2: 1024-wide scan over 2048 bins (2 bins/thread)
    int b0 = t * 2;
    int c0 = lcur[b0], c1 = lcur[b0 + 1];
    tsum[t] = c0 + c1;
    __syncthreads();
    for (int o = 1; o < 1024; o <<= 1) {
        int a = (t >= o) ? tsum[t - o] : 0;
        __syncthreads();
        tsum[t] += a;
        __syncthreads();
    }
    int excl = tsum[t] - (c0 + c1);
    lstart[b0] = excl;
    lstart[b0 + 1] = excl + c0;
    if (t == 1023) lstart[NBUCK] = excl + c0 + c1;   // S = edges in tile
    gshift[b0]     = Bstart[b0]     + H[b * NBUCK + b0]     - excl;
    gshift[b0 + 1] = Bstart[b0 + 1] + H[b * NBUCK + b0 + 1] - (excl + c0);
    lcur[b0] = excl;
    lcur[b0 + 1] = excl + c0;
    __syncthreads();
    // phase 3: place into LDS in bucket-sorted order
    {
        int dd[16], sx[16]; float wv[16]; bool ok[16];
#pragma unroll
        for (int k = 0; k < 16; k++) {
            int e = b * TE + k * 1024 + t;
            ok[k] = e < E;
            if (ok[k]) { dd[k] = dst[e]; sx[k] = src[e]; wv[k] = w[e]; }
        }
        int pk0[16]; float es[16]; int bin[16];
#pragma unroll
        for (int k = 0; k < 16; k++) {
            if (ok[k]) {
                float v = wv[k];
                float e2 = 0.f;
                if (v > 0.f)      e2 = __expf(v);
                else if (v < 0.f) e2 = -__expf(-v);
                es[k] = e2;
                bin[k] = dd[k] / BNODES;
                pk0[k] = sx[k] | ((dd[k] - bin[k] * BNODES) << 19);
            }
        }
        int p[16];
#pragma unroll
        for (int k = 0; k < 16; k++)
            if (ok[k]) p[k] = atomicAdd(&lcur[bin[k]], 1);
#pragma unroll
        for (int k = 0; k < 16; k++)
            if (ok[k]) {
                int2 pk; pk.x = pk0[k]; pk.y = __float_as_int(es[k]);
                pb[p[k]] = pk;
            }
    }
    __syncthreads();
    // phase 4: linear readout, coalesced global writes (runs per bucket)
    int S = lstart[NBUCK];
    for (int k = 0; k < 16; k++) {
        int i = k * 1024 + t;
        if (i < S) {
            int lo = 0, hi = NBUCK;                 // lstart[0]==0 <= i
            while (hi - lo > 1) {
                int mid = (lo + hi) >> 1;
                if (lstart[mid] <= i) lo = mid; else hi = mid;
            }
            csrB[gshift[lo] + i] = pb[i];
        }
    }
}

// per-bucket counting sort (in place), key = dst_local*2 + sign:
// each node's edges land [positives | negatives].
// Output payload: .x = src(19b) | (d&7)<<19 | sign<<22  (slot id for MFMA agg),
//                 .y = |es| fp32.
__global__ __launch_bounds__(256) void k_sortbucket(
    int2* __restrict__ csrB, const int* __restrict__ Bstart,
    int* __restrict__ cnt, int* __restrict__ cntp, int* __restrict__ offs) {
    __shared__ int2 pb[CAP];
    __shared__ int lcnt[BNODES * 2];
    __shared__ int lpos[BNODES * 2];
    int t = threadIdx.x, b = blockIdx.x;
    int lo = Bstart[b];
    int S  = Bstart[b + 1] - lo;
    if (S > CAP) S = CAP;                        // memory-safety guard
    for (int i = t; i < BNODES * 2; i += 256) lcnt[i] = 0;
    __syncthreads();
    for (int i = t; i < S; i += 256) {
        int2 pk = csrB[lo + i];                  // coalesced
        pb[i] = pk;
        int key = ((pk.x >> 19) << 1) | ((unsigned)pk.y >> 31);
        atomicAdd(&lcnt[key], 1);
    }
    __syncthreads();
    if (t == 0) {
        int s = 0;
        for (int i = 0; i < BNODES * 2; i++) { lpos[i] = s; s += lcnt[i]; }
    }
    __syncthreads();
    int node0 = b * BNODES;
    for (int i = t; i < BNODES; i += 256) {
        cnt[node0 + i]  = lcnt[2 * i] + lcnt[2 * i + 1];
        cntp[node0 + i] = lcnt[2 * i];
        offs[node0 + i] = lo + lpos[2 * i];
    }
    __syncthreads();
    for (int i = t; i < S; i += 256) {
        int2 pk = pb[i];
        int local = pk.x >> 19;
        int sign  = (unsigned)pk.y >> 31;
        int key = (local << 1) | sign;
        int p = atomicAdd(&lpos[key], 1);
        int d7 = (node0 + local) & 7;            // node mod 8 -> slot id bits
        int2 outv;
        outv.x = (pk.x & 0x7FFFF) | (d7 << 19) | (sign << 22);
        outv.y = pk.y & 0x7FFFFFFF;              // |es|
        csrB[lo + p] = outv;                     // bucket-local, L2-hot
    }
}

// ---------------- Layer 1 (h0 = deg, 1 feature -> 32), bf16 output ----------
// 16 lanes/node; epilogue computes 2 features per lane (f, f+16).
// Emits xtab[d] = bf16x4 (c1s*deg, c1p*hp, c1n*hn, 1.0) — the MFMA-agg A operand.

__global__ __launch_bounds__(256) void k_layer1(
    const int* __restrict__ cnt, const int* __restrict__ cntp,
    const int* __restrict__ offs, const int2* __restrict__ csr,
    float* __restrict__ spos, float* __restrict__ sneg,
    unsigned short* __restrict__ h1b,
    unsigned long long* __restrict__ xtab,
    const float* __restrict__ W1, const float* __restrict__ b1,
    const float* __restrict__ bias1,
    const float* __restrict__ c1s, const float* __restrict__ c1p,
    const float* __restrict__ c1n) {
    int t = threadIdx.x;
    int g = t >> 4, f = t & 15;           // 16 groups x 16 lanes
    int d = blockIdx.x * 16 + g;          // NNODES % 16 == 0
    int beg = offs[d];
    int len = cnt[d];
    int np  = cntp[d];
    float sp = 0.f, sn = 0.f, up = 0.f, un = 0.f;
    for (int j = 0; j < len; j += 16) {
        int rem = len - j;
        if (f < rem) {
            int2 sw = csr[beg + j + f];            // coalesced 8B/lane
            float es = __int_as_float(sw.y);        // |es|
            float degs = (float)cnt[sw.x & 0x7FFFF]; // mask slot bits
            float ep = (j + f < np) ? es : 0.f;
            float en = es - ep;
            sp += ep; sn += en;
            up = fmaf(degs, ep, up); un = fmaf(degs, en, un);
        }
    }
#pragma unroll
    for (int m = 8; m; m >>= 1) {
        sp += __shfl_xor(sp, m, 16);
        sn += __shfl_xor(sn, m, 16);
        up += __shfl_xor(up, m, 16);
        un += __shfl_xor(un, m, 16);
    }
    if (f == 0) { spos[d] = sp; sneg[d] = sn; }
    float hp = up / fmaxf(sp, 1e-20f);
    float hn = un / fmaxf(sn, 1e-20f);
    float x0 = c1s[0] * (float)len;   // deg[d] == len
    float x1 = c1p[0] * hp;
    float x2 = c1n[0] * hn;
    if (f == 0) {
        unsigned long long u0 = (unsigned short)f2bf(x0);
        unsigned long long u1 = (unsigned short)f2bf(x1);
        unsigned long long u2 = (unsigned short)f2bf(x2);
        xtab[d] = u0 | (u1 << 16) | (u2 << 32) | (0x3F80ULL << 48); // +1.0
    }
#pragma unroll
    for (int q = 0; q < 2; q++) {
        int ff = f + q * 16;
        float v = W1[ff * 3] * x0 + W1[ff * 3 + 1] * x1 + W1[ff * 3 + 2] * x2
                + b1[ff] + bias1[ff];
        v = fmaxf(v, 0.f);
        h1b[d * 32 + ff] = (unsigned short)f2bf(v);  // bf16 table (MFMA A operand)
    }
}

// ---------------- Layer-2 aggregation via MFMA --------------------------------
// Per wave: 8 nodes = 16 slots (node&7 x sign). Window = 32 edges.
// R15: MFMA1 is ONE v_mfma_f32_32x32x16_bf16 (M=32 edges, N=32 feats, K=16
// with 4 used). A row m = lane&31 == the lane's own edge -> each lane feeds
// its own xtab record: the 2 ds_bpermute broadcasts and quad0-only gather
// masking are gone, and 4 16x16 MFMA1s collapse to 1 wider one.
// C layout (guide): col=lane&31, row=(reg&3)+8*(reg>>2)+4*(lane>>5) -> reg
// quads are 4 consecutive edge-rows => same relu/cvt_pk/b64 store epilogue.
//  MFMA2 (x2, 16x16): OUT[slot16][feat16] += S * H, S one-hot per edge column.
// 3-stage pipeline (R11) retained: load rec[w+2] || derive+gather w+1 || compute w.

struct AggFront {
    int pk;                       // es16 | slot<<16
    unsigned long long r8;        // own edge's xtab record (lanes<32)
};

__global__ __launch_bounds__(256) void k_agg(
    const int* __restrict__ cnt, const int* __restrict__ offs,
    const int2* __restrict__ csr,
    const float* __restrict__ spos, const float* __restrict__ sneg,
    const unsigned long long* __restrict__ xtab,
    const unsigned short* __restrict__ W1Tb,   // [4][32] bf16, row3 = b1+bias1
    unsigned short* __restrict__ hpb, unsigned short* __restrict__ hnb,
    int E) {
    __shared__ unsigned short Hl[4][32][40];   // [wave][feat][edge], stride 80B
    __shared__ unsigned short Sl[4][16][40];   // [wave][slot][edge], stride 80B
    int t = threadIdx.x;
    int wv = t >> 6, lane = t & 63;
    int col = lane & 15, quad = lane >> 4;
    int n32 = lane & 31, half = lane >> 5;
    int d0 = (blockIdx.x * 4 + wv) * 8;
    int beg = offs[d0];
    int totlen = 0;
#pragma unroll
    for (int i = 0; i < 8; i++) totlen += cnt[d0 + i];

    // B1 for 32x32x16: lanes 0-31 hold k=0..7 (W1T rows; only k<4 nonzero),
    // lanes 32-63 hold k=8..15 (all zero).
    bf8 B1;
    {
        u32x4 bw = {0u, 0u, 0u, 0u};
        if (half == 0) {
            unsigned w0 = W1Tb[0 * 32 + n32], w1 = W1Tb[1 * 32 + n32];
            unsigned w2 = W1Tb[2 * 32 + n32], w3 = W1Tb[3 * 32 + n32];
            bw.x = w0 | (w1 << 16);
            bw.y = w2 | (w3 << 16);
        }
        B1 = __builtin_bit_cast(bf8, bw);
    }

    f4 acc2[2] = {{0.f, 0.f, 0.f, 0.f}, {0.f, 0.f, 0.f, 0.f}};
    unsigned short (*myH)[40] = Hl[wv];
    unsigned short (*myS)[40] = Sl[wv];
    int nw = (totlen + 31) >> 5;

    auto LDREC = [&](int w) -> long long {
        int eidx = w * 32 + n32;
        int gidx = beg + ((eidx < totlen) ? eidx : 0);
        gidx = gidx < E ? gidx : E - 1;            // guard (empty-group case)
        return *(const long long*)(csr + gidx);    // halves duplicate
    };
    auto DERIVE = [&](long long rec, int w, AggFront& f) {
        int x = (int)rec;
        float ef = __int_as_float((int)(rec >> 32));   // |es|
        int eidx = w * 32 + n32;
        int slot = (eidx < totlen) ? (((x >> 19) & 7) * 2 + ((x >> 22) & 1)) : 255;
        unsigned es16 = (unsigned)(unsigned short)f2bf(ef);
        f.pk = (int)(es16 | ((unsigned)slot << 16));
        f.r8 = 0;
        if (half == 0)
            f.r8 = xtab[(unsigned)x & 0x7FFFF];        // own edge's src record
    };

    if (nw > 0) {
        AggFront fc, fn;
        long long rec0 = LDREC(0);
        DERIVE(rec0, 0, fc);
        long long recN = (nw > 1) ? LDREC(1) : rec0;

        for (int w = 0; w < nw; w++) {
            // stage: issue next-next record load + next window's derive/gather
            long long recNN = (w + 2 < nw) ? LDREC(w + 2) : recN;
            if (w + 1 < nw) DERIVE(recN, w + 1, fn);
            recN = recNN;

            // ---- compute window w from fc ----
            int slot = ((unsigned)fc.pk >> 16);
            unsigned short es16 = (unsigned short)(fc.pk & 0xFFFF);
            {
                u32x4 z = {0u, 0u, 0u, 0u};
                *(u32x4*)&myS[lane >> 2][(lane & 3) * 8] = z;
            }
            if (lane < 32 && slot < 16)
                myS[slot][n32] = es16;

            // MFMA1: H[32 edges][32 feats] = relu(Xe * W1T), one 32x32x16 op
            {
                u32x4 av = {(unsigned)fc.r8, (unsigned)(fc.r8 >> 32), 0u, 0u};
                bf8 A1 = __builtin_bit_cast(bf8, av);
                f16x h;
#pragma unroll
                for (int i = 0; i < 16; i++) h[i] = 0.f;
                h = __builtin_amdgcn_mfma_f32_32x32x16_bf16(A1, B1, h, 0, 0, 0);
#pragma unroll
                for (int rq = 0; rq < 4; rq++) {
                    float v0 = fmaxf(h[4 * rq + 0], 0.f);
                    float v1 = fmaxf(h[4 * rq + 1], 0.f);
                    float v2 = fmaxf(h[4 * rq + 2], 0.f);
                    float v3 = fmaxf(h[4 * rq + 3], 0.f);
                    unsigned u0, u1;
                    asm("v_cvt_pk_bf16_f32 %0, %1, %2" : "=v"(u0) : "v"(v0), "v"(v1));
                    asm("v_cvt_pk_bf16_f32 %0, %1, %2" : "=v"(u1) : "v"(v2), "v"(v3));
                    int rb = rq * 8 + 4 * half;    // edge-row base of this reg quad
                    *(unsigned long long*)&myH[n32][rb] =
                        (unsigned long long)u0 | ((unsigned long long)u1 << 32);
                }
            }

            // A2 = S[col][quad*8..+8] (one 16B LDS read)
            bf8 A2 = *(const bf8*)&myS[col][quad * 8];

            // MFMA2: acc += S * H (16x16x32, B from [feat][edge] tile)
#pragma unroll
            for (int fh = 0; fh < 2; fh++) {
                bf8 B2 = *(const bf8*)&myH[fh * 16 + col][quad * 8];
                acc2[fh] = __builtin_amdgcn_mfma_f32_16x16x32_bf16(A2, B2, acc2[fh], 0, 0, 0);
            }
            fc = fn;                    // rotate (garbage on last iter, unused)
        }
    }

    // ---- epilogue: normalize per slot, store bf16 ----
#pragma unroll
    for (int i = 0; i < 4; i++) {
        int slot = quad * 4 + i;
        int node = d0 + (slot >> 1);
        float s = (slot & 1) ? sneg[node] : spos[node];
        float r = 1.0f / fmaxf(s, 1e-20f);
        unsigned short* bp = (slot & 1) ? hnb : hpb;
#pragma unroll
        for (int fh = 0; fh < 2; fh++) {
            float v = acc2[fh][i] * r;
            bp[(size_t)node * 32 + fh * 16 + col] = (unsigned short)f2bf(v);
        }
    }
}

// ---------------- weight prep: bf16 transposed, scales folded ---------------

__global__ __launch_bounds__(256) void k_prep(
    const float* __restrict__ W2, const float* __restrict__ c2s,
    const float* __restrict__ c2p, const float* __restrict__ c2n,
    const float* __restrict__ k1,
    const float* __restrict__ W1, const float* __restrict__ b1,
    const float* __restrict__ bias1,
    unsigned short* __restrict__ W2sT, unsigned short* __restrict__ k1T,
    unsigned short* __restrict__ W1Tb) {
    int i = blockIdx.x * 256 + threadIdx.x;
    if (i < 96 * 32) {
        int k = i >> 5, n = i & 31;
        float sc = (k < 32) ? c2s[0] : ((k < 64) ? c2p[0] : c2n[0]);
        W2sT[i] = (unsigned short)f2bf(W2[n * 96 + k] * sc);
    } else if (i < 96 * 32 + 64 * 16) {
        int j = i - 3072;
        int k = j >> 4, o = j & 15;
        k1T[j] = (unsigned short)f2bf(k1[o * 64 + k]);
    } else if (i < 96 * 32 + 64 * 16 + 4 * 32) {
        int j = i - (3072 + 1024);
        int k = j >> 5, n = j & 31;
        float v = (k < 3) ? W1[n * 3 + k] : (b1[n] + bias1[n]);
        W1Tb[j] = (unsigned short)f2bf(v);
    }
}

// ---------------- Layer-2 MLP + conv1 via MFMA ------------------------------

__global__ __launch_bounds__(256) void k_mlp_mfma(
    const unsigned short* __restrict__ h1b,
    const unsigned short* __restrict__ hpb, const unsigned short* __restrict__ hnb,
    const unsigned short* __restrict__ W2sT, const unsigned short* __restrict__ k1T,
    const float* __restrict__ b2, const float* __restrict__ bias2,
    const float* __restrict__ bk1,
    float* __restrict__ y1) {
    __shared__ unsigned short h2s[4][16 * 32];     // per-wave transpose tile
    int t = threadIdx.x;
    int wv = t >> 6;
    int lane = t & 63;
    int col = lane & 15;
    int quad = lane >> 4;

    float bv0 = b2[col] + bias2[col];
    float bv1 = b2[col + 16] + bias2[col + 16];
    float bky = bk1[col];

    bf8 BW[2][3];
#pragma unroll
    for (int nt = 0; nt < 2; nt++)
#pragma unroll
        for (int kt = 0; kt < 3; kt++) {
            bf8 b;
#pragma unroll
            for (int j = 0; j < 8; j++)
                b[j] = (short)W2sT[(kt * 32 + quad * 8 + j) * 32 + nt * 16 + col];
            BW[nt][kt] = b;
        }
    bf8 BK[2];
#pragma unroll
    for (int kt = 0; kt < 2; kt++) {
        bf8 b;
#pragma unroll
        for (int j = 0; j < 8; j++)
            b[j] = (short)k1T[(kt * 32 + quad * 8 + j) * 16 + col];
        BK[kt] = b;
    }
    unsigned short* myT = h2s[wv];

#pragma unroll 1
    for (int g = 0; g < 4; g++) {
        int nbase = blockIdx.x * 256 + wv * 64 + g * 16;
        int node = nbase + col;                     // A-operand row m = col
        bf8 a0 = *(const bf8*)(h1b + (size_t)node * 32 + quad * 8);
        bf8 a1 = *(const bf8*)(hpb + (size_t)node * 32 + quad * 8);
        bf8 a2 = *(const bf8*)(hnb + (size_t)node * 32 + quad * 8);

        f4 acc0 = {bv0, bv0, bv0, bv0};
        f4 acc1 = {bv1, bv1, bv1, bv1};
        acc0 = __builtin_amdgcn_mfma_f32_16x16x32_bf16(a0, BW[0][0], acc0, 0, 0, 0);
        acc0 = __builtin_amdgcn_mfma_f32_16x16x32_bf16(a1, BW[0][1], acc0, 0, 0, 0);
        acc0 = __builtin_amdgcn_mfma_f32_16x16x32_bf16(a2, BW[0][2], acc0, 0, 0, 0);
        acc1 = __builtin_amdgcn_mfma_f32_16x16x32_bf16(a0, BW[1][0], acc1, 0, 0, 0);
        acc1 = __builtin_amdgcn_mfma_f32_16x16x32_bf16(a1, BW[1][1], acc1, 0, 0, 0);
        acc1 = __builtin_amdgcn_mfma_f32_16x16x32_bf16(a2, BW[1][2], acc1, 0, 0, 0);

#pragma unroll
        for (int i = 0; i < 4; i++) {
            int r = quad * 4 + i;
            myT[r * 32 + col]      = (unsigned short)f2bf(fmaxf(acc0[i], 0.f));
            myT[r * 32 + col + 16] = (unsigned short)f2bf(fmaxf(acc1[i], 0.f));
        }
        bf8 ah2 = *(const bf8*)(myT + col * 32 + quad * 8);

        f4 accy = {bky, bky, bky, bky};
        accy = __builtin_amdgcn_mfma_f32_16x16x32_bf16(a0,  BK[0], accy, 0, 0, 0);
        accy = __builtin_amdgcn_mfma_f32_16x16x32_bf16(ah2, BK[1], accy, 0, 0, 0);
#pragma unroll
        for (int i = 0; i < 4; i++)
            y1[(size_t)(nbase + quad * 4 + i) * 16 + col] = accy[i];
    }
}

// ---------------- Wfc repack: vec4-friendly layout for the head FC ----------
// W4[(c>>2)*512 + u*4 + (c&3)] = Wfc[u*416+c]: 4 consecutive input-terms
// contiguous per output -> FC reads one float4 per 4 terms, coalesced.

__global__ void k_transpose(const float* __restrict__ Wfc, float* __restrict__ W4) {
    int i = blockIdx.x * 256 + threadIdx.x;
    if (i < 128 * 416) {
        int u = i / 416, c = i - u * 416;
        W4[(c >> 2) * 512 + u * 4 + (c & 3)] = Wfc[i];
    }
}

// ---------------- Head: maxpool -> conv2 -> FC -> classifier -> log_softmax ----
// R14: GH=8 graphs per block (grid 512). Conv front-end per graph into
// xr_all[8][416]; the FC loads each W4 float4 ONCE and applies it to all 8
// graphs (8 independent accumulators). Weight L2 traffic drops 8x (850->106MB)
// and the 8 fma-chains per load give MLP without extra batching.

__global__ __launch_bounds__(256) void k_head(
    const float* __restrict__ y1, const float* __restrict__ k2,
    const float* __restrict__ bk2, const float* __restrict__ W4,
    const float* __restrict__ bfc, const float* __restrict__ Wc,
    const float* __restrict__ bc, float* __restrict__ out) {
    __shared__ float yl[1296];          // 81 positions x 16 ch
    __shared__ float zl[16][41];        // after maxpool, pad
    __shared__ float k2s[1536];
    __shared__ float xr_all[GH][416];   // conv2 out per graph
    __shared__ float fl2s[2][128 * GH]; // FC half-partials [q][u*GH+g]
    __shared__ float fl_all[GH][128];
    __shared__ float ll[GH][10];
    int t = threadIdx.x;
    int b0 = blockIdx.x * GH;
    for (int i = t; i < 1536; i += 256) k2s[i] = k2[i];
    // conv front-end, one graph at a time (yl/zl reused)
    for (int g = 0; g < GH; g++) {
        const float4* yb4 = (const float4*)(y1 + (size_t)(b0 + g) * 1296);
        __syncthreads();
        for (int i = t; i < 324; i += 256) ((float4*)yl)[i] = yb4[i];
        __syncthreads();
        for (int i = t; i < 640; i += 256) {
            int ic = i & 15, p = i >> 4;
            zl[ic][p] = fmaxf(yl[(2 * p) * 16 + ic], yl[(2 * p + 1) * 16 + ic]);
        }
        __syncthreads();
        for (int i = t; i < 416; i += 256) {
            int oc = i / 13, tt = i - oc * 13;
            float acc = bk2[oc];
            for (int ic = 0; ic < 16; ic++) {
                const float* kk = &k2s[(oc * 16 + ic) * 3];
                acc += zl[ic][3 * tt]     * kk[0]
                     + zl[ic][3 * tt + 1] * kk[1]
                     + zl[ic][3 * tt + 2] * kk[2];
            }
            xr_all[g][i] = acc;
        }
    }
    __syncthreads();
    // FC 416 -> 128: 2 threads per output u, 52 chunks each; weight float4
    // loaded once, reused across GH graphs.
    {
        int u = t & 127, q = t >> 7;
        const float* Wb = W4 + u * 4;
        float acc[GH];
#pragma unroll
        for (int g = 0; g < GH; g++) acc[g] = 0.f;
        int base = q * 52;
#pragma unroll 2
        for (int i4 = base; i4 < base + 52; i4++) {
            float4 wv = *(const float4*)(Wb + (size_t)i4 * 512);
#pragma unroll
            for (int g = 0; g < GH; g++) {
                float4 xv = *(const float4*)&xr_all[g][i4 * 4];  // broadcast read
                acc[g] = fmaf(xv.x, wv.x,
                         fmaf(xv.y, wv.y,
                         fmaf(xv.z, wv.z, fmaf(xv.w, wv.w, acc[g]))));
            }
        }
#pragma unroll
        for (int g = 0; g < GH; g++) fl2s[q][u * GH + g] = acc[g];
    }
    __syncthreads();
    if (t < 128) {
        float bv = bfc[t];
#pragma unroll
        for (int g = 0; g < GH; g++)
            fl_all[g][t] = fmaxf(fl2s[0][t * GH + g] + fl2s[1][t * GH + g] + bv, 0.f);
    }
    __syncthreads();
    // classifier: 16 lanes per class, shfl reduce, looped over graphs
    if (t < 160) {
        int c = t >> 4, l = t & 15;
        for (int g = 0; g < GH; g++) {
            float acc = 0.f;
            const float* fl = fl_all[g];
            for (int i = l * 8; i < l * 8 + 8; i++)
                acc += fl[i] * Wc[c * 128 + i];
            for (int m = 8; m; m >>= 1) acc += __shfl_down(acc, m, 16);
            if (l == 0) ll[g][c] = acc + bc[c];
        }
    }
    __syncthreads();
    if (t < GH * 10) {
        int g = t / 10, c = t - g * 10;
        const float* lg = ll[g];
        float m = -1e30f;
        for (int k = 0; k < 10; k++) m = fmaxf(m, lg[k]);
        float s = 0.f;
        for (int k = 0; k < 10; k++) s += __expf(lg[k] - m);
        out[(b0 + g) * 10 + c] = lg[c] - m - __logf(s);
    }
}

// ---------------- launch ----------------

extern "C" void kernel_launch(void* const* d_in, const int* in_sizes, int n_in,
                              void* d_out, int out_size, void* d_ws, size_t ws_size,
                              hipStream_t stream) {
    const int*   src   = (const int*)d_in[0];
    const int*   dst   = (const int*)d_in[1];
    const float* w     = (const float*)d_in[2];
    const float* W1    = (const float*)d_in[4];
    const float* b1    = (const float*)d_in[5];
    const float* bias1 = (const float*)d_in[6];
    const float* c1s   = (const float*)d_in[7];
    const float* c1p   = (const float*)d_in[8];
    const float* c1n   = (const float*)d_in[9];
    const float* W2    = (const float*)d_in[10];
    const float* b2    = (const float*)d_in[11];
    const float* bias2 = (const float*)d_in[12];
    const float* c2s   = (const float*)d_in[13];
    const float* c2p   = (const float*)d_in[14];
    const float* c2n   = (const float*)d_in[15];
    const float* k1    = (const float*)d_in[16];
    const float* bk1   = (const float*)d_in[17];
    const float* k2    = (const float*)d_in[18];
    const float* bk2   = (const float*)d_in[19];
    const float* Wfc   = (const float*)d_in[20];
    const float* bfc   = (const float*)d_in[21];
    const float* Wc    = (const float*)d_in[22];
    const float* bc    = (const float*)d_in[23];
    const int E = in_sizes[0];
    const int NT = (E + TE - 1) / TE;
    const int CS = (NT + CH - 1) / CH;

    // workspace carve (256B aligned) — xtab aliases y1 (read before y1 written)
    size_t off = 0;
    auto carve = [&](size_t bytes) -> char* {
        char* p = (char*)d_ws + off;
        off = (off + bytes + 255) & ~(size_t)255;
        return p;
    };
    int*   cnt    = (int*)  carve((size_t)NNODES * 4);
    int*   cntp   = (int*)  carve((size_t)NNODES * 4);
    int*   offs   = (int*)  carve((size_t)NNODES * 4);
    int2*  csrB   = (int2*) carve((size_t)E * 8);
    int*   H      = (int*)  carve((size_t)NT * NBUCK * 4);
    int*   P      = (int*)  carve((size_t)CH * NBUCK * 4);
    int*   T      = (int*)  carve((size_t)NBUCK * 4);
    int*   Bstart = (int*)  carve((size_t)(NBUCK + 1) * 4);
    float* spos   = (float*)carve((size_t)NNODES * 4);
    float* sneg   = (float*)carve((size_t)NNODES * 4);
    unsigned short* h1b = (unsigned short*)carve((size_t)NNODES * 32 * 2);
    unsigned short* hpb = (unsigned short*)carve((size_t)NNODES * 32 * 2);
    unsigned short* hnb = (unsigned short*)carve((size_t)NNODES * 32 * 2);
    float* y1     = (float*)carve((size_t)NNODES * 16 * 4);
    float* WfcT   = (float*)carve((size_t)128 * 416 * 4);
    unsigned short* W2sT = (unsigned short*)carve((size_t)96 * 32 * 2);
    unsigned short* k1T  = (unsigned short*)carve((size_t)64 * 16 * 2);
    unsigned short* W1Tb = (unsigned short*)carve((size_t)4 * 32 * 2);
    unsigned long long* xtab = (unsigned long long*)y1;  // alias: 2.65MB << y1
    (void)ws_size;

    k_hist      <<<NT, 256, 0, stream>>>(dst, H, E);
    k_colA      <<<CH * NBUCK / 256, 256, 0, stream>>>(H, P, NT, CS);
    k_colB      <<<NBUCK / 256, 256, 0, stream>>>(P, T);
    k_colC      <<<CH * NBUCK / 256, 256, 0, stream>>>(H, P, NT, CS);
    k_binscan   <<<1, 256, 0, stream>>>(T, Bstart);
    k_place     <<<NT, 1024, 0, stream>>>(src, dst, w, H, Bstart, csrB, E);
    k_sortbucket<<<NBUCK, 256, 0, stream>>>(csrB, Bstart, cnt, cntp, offs);
    k_layer1    <<<NNODES / 16, 256, 0, stream>>>(cnt, cntp, offs, csrB,
                                                  spos, sneg, h1b, xtab,
                                                  W1, b1, bias1, c1s, c1p, c1n);
    k_prep      <<<17, 256, 0, stream>>>(W2, c2s, c2p, c2n, k1,
                                         W1, b1, bias1, W2sT, k1T, W1Tb);
    k_transpose <<<(128 * 416 + 255) / 256, 256, 0, stream>>>(Wfc, WfcT);
    k_agg       <<<NNODES / 32, 256, 0, stream>>>(cnt, offs, csrB,
                                                  spos, sneg, xtab, W1Tb,
                                                  hpb, hnb, E);
    k_mlp_mfma  <<<NNODES / 256, 256, 0, stream>>>(h1b, hpb, hnb, W2sT, k1T,
                                                   b2, bias2, bk1, y1);
    k_head      <<<NGRAPH / GH, 256, 0, stream>>>(y1, k2, bk2, WfcT, bfc, Wc, bc,
                                                  (float*)d_out);
}